// Round 3
// baseline (486.250 us; speedup 1.0000x reference)
//
#include <hip/hip_runtime.h>
#include <hip/hip_bf16.h>

#define M_SAMPLES 524288
#define NRAYS 8192
#define GXD 160
#define GYD 160
#define GZD 128
#define GYZ (GYD*GZD)
#define NVOX (GXD*GYD*GZD)
#define ACT_SHIFT -13.81550955796f
#define ROWA 136      // hA leading dim (shorts)
#define ROWB 136      // hB leading dim (shorts)
#define SAMP 64       // samples per tile
#define NTILES (M_SAMPLES/SAMP)   // 8192
#define GRID_MLP 768  // persistent: 3 blocks/CU x 256 CUs

typedef __bf16 bf16x8 __attribute__((ext_vector_type(8)));
typedef float f32x4 __attribute__((ext_vector_type(4)));
typedef float f32x16 __attribute__((ext_vector_type(16)));
typedef float f32v2 __attribute__((ext_vector_type(2)));

static __device__ inline unsigned short f2bf(float f){
  __hip_bfloat16 h = __float2bfloat16(f);
  unsigned short u; __builtin_memcpy(&u, &h, 2); return u;
}
static __device__ inline float flo(unsigned int u){ return __uint_as_float(u << 16); }
static __device__ inline float fhi(unsigned int u){ return __uint_as_float(u & 0xffff0000u); }

#if defined(__has_builtin)
#if __has_builtin(__builtin_amdgcn_cvt_pk_bf16_f32)
#define HAVE_PK_BF16 1
#endif
#if __has_builtin(__builtin_amdgcn_cvt_pk_f32_fp8) && __has_builtin(__builtin_amdgcn_cvt_pk_fp8_f32)
#define HAVE_FP8 1
#endif
#endif

static __device__ inline unsigned int packbf(float a, float b){
#ifdef HAVE_PK_BF16
  typedef __bf16 bf16v2 __attribute__((ext_vector_type(2)));
  bf16v2 r = __builtin_amdgcn_cvt_pk_bf16_f32(a, b);
  unsigned int u; __builtin_memcpy(&u, &r, 4); return u;
#else
  return (unsigned int)f2bf(a) | ((unsigned int)f2bf(b) << 16);
#endif
}

struct Tri {
  int ix, iy, iz;
  float wx0, wx1, wy0, wy1, wz0, wz1;
};
static __device__ inline Tri tri_setup(float x, float y, float z){
  Tri t;
  float tx = (x+1.f)*0.5f*(float)(GXD-1); tx = fminf(fmaxf(tx,0.f),(float)(GXD-1));
  float ty = (y+1.f)*0.5f*(float)(GYD-1); ty = fminf(fmaxf(ty,0.f),(float)(GYD-1));
  float tz = (z+1.f)*0.5f*(float)(GZD-1); tz = fminf(fmaxf(tz,0.f),(float)(GZD-1));
  t.ix = min((int)tx, GXD-2); t.iy = min((int)ty, GYD-2); t.iz = min((int)tz, GZD-2);
  float fx = tx-t.ix, fy = ty-t.iy, fz = tz-t.iz;
  t.wx0 = 1.f-fx; t.wx1 = fx; t.wy0 = 1.f-fy; t.wy1 = fy; t.wz0 = 1.f-fz; t.wz1 = fz;
  return t;
}

// ---------------- merged prologue: repack | detect | weights | ray view-term ---
#define NB_REPACK (NVOX/256)              // 12800
#define NB_W      184                     // ceil(47104/256)
#define NB_RT     (NRAYS/256)             // 32
__global__ __launch_bounds__(256) void k_prep(
    const float* __restrict__ density, const float* __restrict__ k0,
    uint4* __restrict__ packed,
    const unsigned int* __restrict__ mw, int* __restrict__ flag,
    const float* __restrict__ W0, const float* __restrict__ W1,
    const float* __restrict__ W2, const float* __restrict__ Wr,
    const float* __restrict__ br,
    unsigned short* __restrict__ wt0, unsigned short* __restrict__ wt1,
    unsigned short* __restrict__ wt2, unsigned short* __restrict__ wtr,
    const float* __restrict__ vd, float* __restrict__ rayterm3)
{
  int b = blockIdx.x;
  if(b < NB_REPACK){
    int v = b*256 + threadIdx.x;
    const float4* kp = (const float4*)(k0 + (size_t)v*12);
    float4 a = kp[0], bb = kp[1], c = kp[2];
#ifdef HAVE_FP8
    uint4 o;
    o.x = __float_as_uint(density[v]);
    int w;
    w = __builtin_amdgcn_cvt_pk_fp8_f32(a.x, a.y, 0, false);
    w = __builtin_amdgcn_cvt_pk_fp8_f32(a.z, a.w, w, true);
    o.y = (unsigned int)w;
    w = __builtin_amdgcn_cvt_pk_fp8_f32(bb.x, bb.y, 0, false);
    w = __builtin_amdgcn_cvt_pk_fp8_f32(bb.z, bb.w, w, true);
    o.z = (unsigned int)w;
    w = __builtin_amdgcn_cvt_pk_fp8_f32(c.x, c.y, 0, false);
    w = __builtin_amdgcn_cvt_pk_fp8_f32(c.z, c.w, w, true);
    o.w = (unsigned int)w;
    packed[v] = o;
#else
    uint4 o0, o1;
    o0.x = __float_as_uint(density[v]);
    o0.y = packbf(a.x, a.y); o0.z = packbf(a.z, a.w); o0.w = packbf(bb.x, bb.y);
    o1.x = packbf(bb.z, bb.w); o1.y = packbf(c.x, c.y); o1.z = packbf(c.z, c.w);
    o1.w = 0;
    packed[(size_t)v*2]   = o0;
    packed[(size_t)v*2+1] = o1;
#endif
    return;
  }
  if(b == NB_REPACK){
    unsigned int v = mw[threadIdx.x & 63];
    unsigned long long any = __ballot(v > 1u);
    if(threadIdx.x == 0) *flag = (any != 0ull) ? 1 : 0;   // 1 = byte mask
    return;
  }
  if(b < NB_REPACK + 1 + NB_W){
    int t = (b - NB_REPACK - 1)*256 + threadIdx.x;
    if(t < 128*96){
      int n = t/96, k = t%96;
      wt0[t] = f2bf((k < 75) ? W0[k*128 + n] : 0.f);
    } else if(t < 128*96 + 16384){
      int j = t - 128*96; int n = j/128, k = j%128;
      wt1[j] = f2bf(W1[k*128 + n]);
    } else if(t < 128*96 + 32768){
      int j = t - 128*96 - 16384; int n = j/128, k = j%128;
      wt2[j] = f2bf(W2[k*128 + n]);
    } else if(t < 128*96 + 32768 + 16*128){
      int j = t - 128*96 - 32768; int n = j/128, k = j%128;
      wtr[j] = f2bf((n < 3) ? Wr[k*3 + n] : 0.f);
    }
    return;
  }
  // per-ray view term: rayterm3[ray][c] = br[c] + sum_j ve_j * Wr[(128+j)*3+c]
  int ray = (b - NB_REPACK - 1 - NB_W)*256 + threadIdx.x;
  if(ray >= NRAYS) return;
  float v0 = vd[ray*3+0], v1 = vd[ray*3+1], v2 = vd[ray*3+2];
  float vej[27];
  vej[0] = v0; vej[1] = v1; vej[2] = v2;
  #pragma unroll
  for(int ci = 0; ci < 3; ++ci){
    float xv = (ci == 0) ? v0 : ((ci == 1) ? v1 : v2);
    #pragma unroll
    for(int p = 0; p < 4; ++p){
      float arg = xv * (float)(1 << p);
      vej[3 + ci*4 + p]  = __sinf(arg);
      vej[15 + ci*4 + p] = __cosf(arg);
    }
  }
  float rt0 = br[0], rt1 = br[1], rt2 = br[2];
  #pragma unroll
  for(int j = 0; j < 27; ++j){
    const float* wr = Wr + (128 + j)*3;
    rt0 += vej[j]*wr[0]; rt1 += vej[j]*wr[1]; rt2 += vej[j]*wr[2];
  }
  rayterm3[ray*3+0] = rt0; rayterm3[ray*3+1] = rt1; rayterm3[ray*3+2] = rt2;
}

// ---------------- MFMA layer: weights from registers, activations from LDS ----
template<int KDIM, int SROW>
static __device__ __forceinline__ void mfma_layer(const unsigned short* src,
    const f32x4* wf, f32x16& acc0, f32x16& acc1, int ln, int kh)
{
  constexpr int NS = KDIM/16;
  const unsigned short* abase0 = src + (ln)*SROW + kh*8;
  const unsigned short* abase1 = src + (32 + ln)*SROW + kh*8;
  f32x16 z = {0.f,0.f,0.f,0.f,0.f,0.f,0.f,0.f,0.f,0.f,0.f,0.f,0.f,0.f,0.f,0.f};
  acc0 = z; acc1 = z;
  __builtin_amdgcn_s_setprio(1);
  #pragma unroll
  for(int st = 0; st < NS; ++st){
    bf16x8 a0 = *(const bf16x8*)(abase0 + st*16);
    bf16x8 a1 = *(const bf16x8*)(abase1 + st*16);
    bf16x8 wv = __builtin_bit_cast(bf16x8, wf[st]);
    acc0 = __builtin_amdgcn_mfma_f32_32x32x16_bf16(wv, a0, acc0, 0, 0, 0);
    acc1 = __builtin_amdgcn_mfma_f32_32x32x16_bf16(wv, a1, acc1, 0, 0, 0);
  }
  __builtin_amdgcn_s_setprio(0);
}

// epilogue: bias (from LDS) + ReLU + bf16 pack -> LDS
template<int DROW>
static __device__ __forceinline__ void epilogue(const f32x16& acc0, const f32x16& acc1,
    unsigned short* dst, const float* sbias, int tile_n, int ln, int kh)
{
  float4 bv[4];
  #pragma unroll
  for(int g = 0; g < 4; ++g) bv[g] = *(const float4*)(sbias + tile_n*32 + g*8 + kh*4);
  #pragma unroll
  for(int rep = 0; rep < 2; ++rep){
    const f32x16& acc = rep ? acc1 : acc0;
    int scol = rep*32 + ln;
    #pragma unroll
    for(int g = 0; g < 4; ++g){
      int n0 = tile_n*32 + g*8 + kh*4;
      unsigned int lo = packbf(fmaxf(acc[4*g+0] + bv[g].x, 0.f), fmaxf(acc[4*g+1] + bv[g].y, 0.f));
      unsigned int hi = packbf(fmaxf(acc[4*g+2] + bv[g].z, 0.f), fmaxf(acc[4*g+3] + bv[g].w, 0.f));
      unsigned long long o = (unsigned long long)lo | ((unsigned long long)hi << 32);
      *(unsigned long long*)(dst + scol*DROW + n0) = o;
    }
  }
}

// ---------------- fused persistent kernel: gather+alpha + MLP + head -----------
// 3 blocks/CU, each block loops over ~11 tiles of 64 samples.
// Cross-tile pipeline: gather loads for tile t+1 are issued before the MFMA
// chain of tile t and stay in flight across it (MFMA chain has NO global loads:
// wf1/wf2 register-resident, biases in LDS, wf0/head/rayterm issued older than
// the gather prefetch so their waits never drain it).
template<int PACKED>
__global__ __launch_bounds__(256, 3) void k_mlp(const float* __restrict__ xyz,
    const uint4* __restrict__ packed,
    const float* __restrict__ density, const float* __restrict__ k0,
    const void* __restrict__ mask, const int* __restrict__ flag,
    const int* __restrict__ ray_id,
    const unsigned short* __restrict__ wt0, const unsigned short* __restrict__ wt1,
    const unsigned short* __restrict__ wt2, const unsigned short* __restrict__ wtr,
    const float* __restrict__ b0, const float* __restrict__ b1,
    const float* __restrict__ b2,
    const float* __restrict__ rayterm3, float4* __restrict__ rgba_out)
{
  __shared__ alignas(16) unsigned short hA[SAMP*ROWA];
  __shared__ alignas(16) unsigned short hB[SAMP*ROWB];
  __shared__ float red[SAMP][4];
  __shared__ int ray_s[SAMP];
  __shared__ alignas(16) float sb[384];   // b0|b1|b2 staged

  int tid = threadIdx.x;
  int lane = tid & 63, wave = tid >> 6;
  int ln = lane & 31, kh = lane >> 5;
  int col = lane & 15, q4 = lane >> 4;
  int smp_a = tid >> 2, corner = tid & 3;
  int dxc = corner & 1, dyc = corner >> 1;
  int smp_b = tid & 63, chunk = 1 + (tid >> 6);
  int flg = *flag;

  if(tid < 96){
    int which = tid >> 5, j = tid & 31;
    const float* bs = (which == 0) ? b0 : ((which == 1) ? b1 : b2);
    *(float4*)(sb + which*128 + j*4) = *(const float4*)(bs + j*4);
  }

  // resident weights for layers 1 & 2; pinned so the compiler can't re-sink them
  f32x4 wf1[8], wf2[8];
  {
    const unsigned short* w1b = wt1 + (wave*32 + ln)*128 + kh*8;
    const unsigned short* w2b = wt2 + (wave*32 + ln)*128 + kh*8;
    #pragma unroll
    for(int st = 0; st < 8; ++st){
      wf1[st] = *(const f32x4*)(w1b + st*16);
      wf2[st] = *(const f32x4*)(w2b + st*16);
    }
  }
  #pragma unroll
  for(int st = 0; st < 8; ++st){
    asm volatile("" : "+v"(wf1[st]));
    asm volatile("" : "+v"(wf2[st]));
  }

  // ---- cross-tile prefetch state --------------------------------------------
  float ax, ay, az, bx, by, bz;     // tile-t xyz (corner role, posemb role)
  float cw0 = 0.f, cw1 = 0.f;       // corner z-weights
  size_t voxs = 0;
  uint4 q0 = {}, q1 = {};
#ifndef HAVE_FP8
  uint4 q2 = {}, q3 = {};
#endif
  int rid = 0; unsigned int mv = 0;

  auto prefetch_gather = [&](int TT){
    Tri tr = tri_setup(ax, ay, az);
    float wxy = (dxc ? tr.wx1 : tr.wx0) * (dyc ? tr.wy1 : tr.wy0);
    cw0 = wxy*tr.wz0; cw1 = wxy*tr.wz1;
    voxs = (size_t)((tr.ix+dxc)*GYZ + (tr.iy+dyc)*GZD + tr.iz);
    if(PACKED){
#ifdef HAVE_FP8
      q0 = packed[voxs]; q1 = packed[voxs+1];
#else
      const uint4* pv = packed + voxs*2;
      q0 = pv[0]; q1 = pv[1]; q2 = pv[2]; q3 = pv[3];
#endif
    }
    if(corner == 0){
      int mx = (int)rintf(ax*79.5f + 79.5f); mx = min(max(mx,0), GXD-1);
      int my = (int)rintf(ay*79.5f + 79.5f); my = min(max(my,0), GYD-1);
      int mz = (int)rintf(az*63.5f + 63.5f); mz = min(max(mz,0), GZD-1);
      int midx = mx*GYZ + my*GZD + mz;
      mv = flg ? (unsigned int)(((const unsigned char*)mask)[midx])
               : ((const unsigned int*)mask)[midx];
    } else if(corner == 1){
      rid = ray_id[TT*SAMP + smp_a];
    }
  };

  // prologue: fully prefetch first tile
  int t = blockIdx.x;
  {
    int ia = t*SAMP + smp_a;
    ax = xyz[3*ia+0]; ay = xyz[3*ia+1]; az = xyz[3*ia+2];
    int ib = t*SAMP + smp_b;
    bx = xyz[3*ib+0]; by = xyz[3*ib+1]; bz = xyz[3*ib+2];
  }
  prefetch_gather(t);

  for(; t < NTILES; t += GRID_MLP){
    int nt = t + GRID_MLP;
    bool has_next = nt < NTILES;
    int blk = t*SAMP;

    // step1: issue next tile's xyz early (hides under gather math)
    float nax=0.f, nay=0.f, naz=0.f, nbx=0.f, nby=0.f, nbz=0.f;
    if(has_next){
      int ia = nt*SAMP + smp_a;
      nax = xyz[3*ia+0]; nay = xyz[3*ia+1]; naz = xyz[3*ia+2];
      int ib = nt*SAMP + smp_b;
      nbx = xyz[3*ib+0]; nby = xyz[3*ib+1]; nbz = xyz[3*ib+2];
    }
    __builtin_amdgcn_sched_barrier(0);

    // step2: gather math for tile t (q already in registers)
    {
      float pd;
      float pf[12];
#ifdef HAVE_FP8
      if(PACKED){
        pd = cw0*__uint_as_float(q0.x) + cw1*__uint_as_float(q1.x);
        f32v2 a, b;
        a = __builtin_amdgcn_cvt_pk_f32_fp8((int)q0.y, false);
        b = __builtin_amdgcn_cvt_pk_f32_fp8((int)q1.y, false);
        pf[0] = cw0*a.x + cw1*b.x;  pf[1] = cw0*a.y + cw1*b.y;
        a = __builtin_amdgcn_cvt_pk_f32_fp8((int)q0.y, true);
        b = __builtin_amdgcn_cvt_pk_f32_fp8((int)q1.y, true);
        pf[2] = cw0*a.x + cw1*b.x;  pf[3] = cw0*a.y + cw1*b.y;
        a = __builtin_amdgcn_cvt_pk_f32_fp8((int)q0.z, false);
        b = __builtin_amdgcn_cvt_pk_f32_fp8((int)q1.z, false);
        pf[4] = cw0*a.x + cw1*b.x;  pf[5] = cw0*a.y + cw1*b.y;
        a = __builtin_amdgcn_cvt_pk_f32_fp8((int)q0.z, true);
        b = __builtin_amdgcn_cvt_pk_f32_fp8((int)q1.z, true);
        pf[6] = cw0*a.x + cw1*b.x;  pf[7] = cw0*a.y + cw1*b.y;
        a = __builtin_amdgcn_cvt_pk_f32_fp8((int)q0.w, false);
        b = __builtin_amdgcn_cvt_pk_f32_fp8((int)q1.w, false);
        pf[8] = cw0*a.x + cw1*b.x;  pf[9] = cw0*a.y + cw1*b.y;
        a = __builtin_amdgcn_cvt_pk_f32_fp8((int)q0.w, true);
        b = __builtin_amdgcn_cvt_pk_f32_fp8((int)q1.w, true);
        pf[10]= cw0*a.x + cw1*b.x;  pf[11]= cw0*a.y + cw1*b.y;
      }
#else
      if(PACKED){
        pd = cw0*__uint_as_float(q0.x) + cw1*__uint_as_float(q2.x);
        pf[0]  = cw0*flo(q0.y) + cw1*flo(q2.y);  pf[1]  = cw0*fhi(q0.y) + cw1*fhi(q2.y);
        pf[2]  = cw0*flo(q0.z) + cw1*flo(q2.z);  pf[3]  = cw0*fhi(q0.z) + cw1*fhi(q2.z);
        pf[4]  = cw0*flo(q0.w) + cw1*flo(q2.w);  pf[5]  = cw0*fhi(q0.w) + cw1*fhi(q2.w);
        pf[6]  = cw0*flo(q1.x) + cw1*flo(q3.x);  pf[7]  = cw0*fhi(q1.x) + cw1*fhi(q3.x);
        pf[8]  = cw0*flo(q1.y) + cw1*flo(q3.y);  pf[9]  = cw0*fhi(q1.y) + cw1*fhi(q3.y);
        pf[10] = cw0*flo(q1.z) + cw1*flo(q3.z);  pf[11] = cw0*fhi(q1.z) + cw1*fhi(q3.z);
      }
#endif
      if(!PACKED){
        pd = cw0*density[voxs] + cw1*density[voxs+1];
        const float4* v = (const float4*)(k0 + voxs*12);
        float4 a0 = v[0], a1 = v[1], a2 = v[2];
        float4 c0 = v[3], c1 = v[4], c2 = v[5];
        pf[0] = cw0*a0.x + cw1*c0.x;  pf[1] = cw0*a0.y + cw1*c0.y;
        pf[2] = cw0*a0.z + cw1*c0.z;  pf[3] = cw0*a0.w + cw1*c0.w;
        pf[4] = cw0*a1.x + cw1*c1.x;  pf[5] = cw0*a1.y + cw1*c1.y;
        pf[6] = cw0*a1.z + cw1*c1.z;  pf[7] = cw0*a1.w + cw1*c1.w;
        pf[8] = cw0*a2.x + cw1*c2.x;  pf[9] = cw0*a2.y + cw1*c2.y;
        pf[10]= cw0*a2.z + cw1*c2.z;  pf[11]= cw0*a2.w + cw1*c2.w;
      }
      #pragma unroll
      for(int m2 = 1; m2 < 4; m2 <<= 1){
        pd += __shfl_xor(pd, m2);
        #pragma unroll
        for(int j = 0; j < 12; ++j) pf[j] += __shfl_xor(pf[j], m2);
      }
      if(corner == 0){
        bool mm = (mv != 0u);
        float e = __expf(pd + ACT_SHIFT);
        float alpha = 1.f - rsqrtf(1.f + e);   // (1+e)^(-0.5), INTERVAL=0.5
        if(!mm) alpha = 0.f;
        red[smp_a][3] = alpha;                 // rides out in rgba.w
        unsigned int d[8];
        #pragma unroll
        for(int j = 0; j < 6; ++j) d[j] = packbf(pf[2*j], pf[2*j+1]);
        d[6] = packbf(ax, ay);
        d[7] = packbf(az, __sinf(ax));         // col 15 = sin(x * 2^0)
        uint4* p = (uint4*)(hA + smp_a*ROWA);
        p[0] = make_uint4(d[0],d[1],d[2],d[3]);
        p[1] = make_uint4(d[4],d[5],d[6],d[7]);
      } else if(corner == 1){
        uint4* p = (uint4*)(hA + smp_a*ROWA + 80);   // cols 80..95 zero
        p[0] = make_uint4(0,0,0,0);
        p[1] = make_uint4(0,0,0,0);
        ray_s[smp_a] = rid;
      }
    }

    // posemb cols 16..79 for this tile (uses bx,by,bz)
    {
      float vv[16];
      #pragma unroll
      for(int j = 0; j < 16; ++j){
        int c = chunk*16 + j;
        float r;
        if(c >= 75) r = 0.f;
        else {
          int q = (c < 45) ? (c-15) : (c-45);
          int ci = q/10, p = q - ci*10;
          float xv = (ci == 0) ? bx : ((ci == 1) ? by : bz);
          float a = xv * (float)(1 << p);
          r = (c < 45) ? __sinf(a) : __cosf(a);
        }
        vv[j] = r;
      }
      unsigned int d[8];
      #pragma unroll
      for(int j = 0; j < 8; ++j) d[j] = packbf(vv[2*j], vv[2*j+1]);
      uint4* p = (uint4*)(hA + smp_b*ROWA + chunk*16);
      p[0] = make_uint4(d[0],d[1],d[2],d[3]);
      p[1] = make_uint4(d[4],d[5],d[6],d[7]);
    }
    __syncthreads();

    // step3: per-tile weight/rayterm loads for THIS tile's MLP/head.
    // Issued BEFORE the gather prefetch batch -> older in the vmem queue ->
    // waiting on them never drains the q(t+1) prefetch.
    f32x4 wf0[6], hwf[4];
    {
      const unsigned short* w0b = wt0 + (wave*32 + ln)*96 + kh*8;
      #pragma unroll
      for(int st = 0; st < 6; ++st) wf0[st] = *(const f32x4*)(w0b + st*16);
      const unsigned short* wrb = wtr + col*128 + q4*8;
      #pragma unroll
      for(int ks = 0; ks < 4; ++ks) hwf[ks] = *(const f32x4*)(wrb + ks*32);
    }
    float rt[4] = {0.f, 0.f, 0.f, 0.f};
    if(col < 3){
      #pragma unroll
      for(int r = 0; r < 4; ++r)
        rt[r] = rayterm3[ray_s[wave*16 + q4*4 + r]*3 + col];
    }
    __builtin_amdgcn_sched_barrier(0);

    // step4: issue gather prefetch for tile t+1 (in flight across MFMA chain)
    if(has_next){
      ax = nax; ay = nay; az = naz; bx = nbx; by = nby; bz = nbz;
      prefetch_gather(nt);
    }
    __builtin_amdgcn_sched_barrier(0);

    // ---- MFMA chain: no global loads anywhere in here -----------------------
    f32x16 acc0, acc1;
    mfma_layer< 96, ROWA>(hA, wf0, acc0, acc1, ln, kh);
    epilogue<ROWB>(acc0, acc1, hB, sb,       wave, ln, kh);
    __syncthreads();
    mfma_layer<128, ROWB>(hB, wf1, acc0, acc1, ln, kh);
    epilogue<ROWA>(acc0, acc1, hA, sb + 128, wave, ln, kh);
    __syncthreads();
    mfma_layer<128, ROWA>(hA, wf2, acc0, acc1, ln, kh);
    epilogue<ROWB>(acc0, acc1, hB, sb + 256, wave, ln, kh);
    __syncthreads();

    // rgb head: 16x16x32 MFMA, K=128, 4 m-tiles = 4 waves; + per-ray view term
    {
      f32x4 acc = {0.f, 0.f, 0.f, 0.f};
      const unsigned short* arow = hB + (wave*16 + col)*ROWB + q4*8;
      __builtin_amdgcn_s_setprio(1);
      #pragma unroll
      for(int ks = 0; ks < 4; ++ks){
        bf16x8 af = *(const bf16x8*)(arow + ks*32);
        acc = __builtin_amdgcn_mfma_f32_16x16x32_bf16(af, __builtin_bit_cast(bf16x8, hwf[ks]), acc, 0, 0, 0);
      }
      __builtin_amdgcn_s_setprio(0);
      if(col < 3){
        #pragma unroll
        for(int r = 0; r < 4; ++r){
          int sl = wave*16 + q4*4 + r;
          float v = acc[r] + rt[r];
          red[sl][col] = __fdividef(1.f, 1.f + __expf(-v));
        }
      }
    }
    __syncthreads();

    // coalesced rgba store (alpha in .w; composite happens in k_comp2)
    if(tid < SAMP){
      rgba_out[blk + tid] = make_float4(red[tid][0], red[tid][1], red[tid][2], red[tid][3]);
    }
    __syncthreads();   // red/hA reused by next iteration's gather
  }
}

// ---------------- per-ray: alpha scan + weighted composite in one pass ---------
__global__ __launch_bounds__(256) void k_comp2(const int* __restrict__ ray_id,
    const float4* __restrict__ rgba, float* __restrict__ out)
{
  int r = blockIdx.x*4 + (threadIdx.x >> 6);   // grid = NRAYS/4 blocks
  int lane = threadIdx.x & 63;
  int lo = 0, hi = M_SAMPLES;
  while(lo < hi){ int mid = (lo+hi) >> 1; if(ray_id[mid] < r) lo = mid+1; else hi = mid; }
  int s = lo;
  int lo2 = s, hi2 = M_SAMPLES;
  while(lo2 < hi2){ int mid = (lo2+hi2) >> 1; if(ray_id[mid] < r+1) lo2 = mid+1; else hi2 = mid; }
  int e = lo2;

  float carry = 1.f;
  float ar = 0.f, ag = 0.f, ab = 0.f;
  for(int base = s; base < e; base += 64){
    int idx = base + lane;
    float4 c = (idx < e) ? rgba[idx] : make_float4(0.f,0.f,0.f,0.f);
    float a = c.w;
    float incl = 1.f - a;
    #pragma unroll
    for(int d2 = 1; d2 < 64; d2 <<= 1){
      float t = __shfl_up(incl, d2);
      if(lane >= d2) incl *= t;
    }
    float excl = __shfl_up(incl, 1);
    if(lane == 0) excl = 1.f;
    float w = carry * excl * a;
    ar += w*c.x; ag += w*c.y; ab += w*c.z;
    carry *= __shfl(incl, 63);
  }
  #pragma unroll
  for(int m2 = 1; m2 < 64; m2 <<= 1){
    ar += __shfl_xor(ar, m2);
    ag += __shfl_xor(ag, m2);
    ab += __shfl_xor(ab, m2);
  }
  if(lane == 0){
    out[3*r+0] = ar + carry;
    out[3*r+1] = ag + carry;
    out[3*r+2] = ab + carry;
  }
}

// ---------------- host ----------------------------------------------------------
extern "C" void kernel_launch(void* const* d_in, const int* in_sizes, int n_in,
                              void* d_out, int out_size, void* d_ws, size_t ws_size,
                              hipStream_t stream)
{
  const float* xyz      = (const float*)d_in[0];
  const int*   ray_id   = (const int*)  d_in[1];
  const float* viewdirs = (const float*)d_in[2];
  const void*  mask     =               d_in[3];
  const float* density  = (const float*)d_in[4];
  const float* k0       = (const float*)d_in[5];
  const float* W0 = (const float*)d_in[6];  const float* b0 = (const float*)d_in[7];
  const float* W1 = (const float*)d_in[8];  const float* b1 = (const float*)d_in[9];
  const float* W2 = (const float*)d_in[10]; const float* b2 = (const float*)d_in[11];
  const float* Wr = (const float*)d_in[12]; const float* br = (const float*)d_in[13];
  float* out = (float*)d_out;

  char* ws = (char*)d_ws;
  size_t off = 0;
  auto take = [&](size_t nbytes) -> void* {
    void* p = ws + off;
    off = (off + nbytes + 255) & ~(size_t)255;
    return p;
  };
  int*            flag     = (int*)           take(4);
  unsigned short* wt0      = (unsigned short*)take(128*96*2);
  unsigned short* wt1      = (unsigned short*)take(128*128*2);
  unsigned short* wt2      = (unsigned short*)take(128*128*2);
  unsigned short* wtr      = (unsigned short*)take(16*128*2);
  float*          rayterm3 = (float*)         take((size_t)NRAYS*3*4);
  float4*         rgba_ws  = (float4*)        take((size_t)M_SAMPLES*16);
#ifdef HAVE_FP8
  uint4*          packed   = (uint4*)         take((size_t)NVOX*16);
#else
  uint4*          packed   = (uint4*)         take((size_t)NVOX*32);
#endif
  bool use_packed = (ws_size >= off);

  k_prep<<<NB_REPACK + 1 + NB_W + NB_RT, 256, 0, stream>>>(
      density, k0, packed, (const unsigned int*)mask, flag,
      W0, W1, W2, Wr, br, wt0, wt1, wt2, wtr, viewdirs, rayterm3);
  if(use_packed){
    k_mlp<1><<<GRID_MLP, 256, 0, stream>>>(xyz, packed, density, k0, mask, flag,
                                           ray_id, wt0, wt1, wt2, wtr,
                                           b0, b1, b2, rayterm3, rgba_ws);
  } else {
    k_mlp<0><<<GRID_MLP, 256, 0, stream>>>(xyz, packed, density, k0, mask, flag,
                                           ray_id, wt0, wt1, wt2, wtr,
                                           b0, b1, b2, rayterm3, rgba_ws);
  }
  k_comp2<<<NRAYS/4, 256, 0, stream>>>(ray_id, rgba_ws, out);
}

// Round 4
// 450.690 us; speedup vs baseline: 1.0789x; 1.0789x over previous
//
#include <hip/hip_runtime.h>
#include <hip/hip_bf16.h>

#define M_SAMPLES 524288
#define NRAYS 8192
#define GXD 160
#define GYD 160
#define GZD 128
#define GYZ (GYD*GZD)
#define NVOX (GXD*GYD*GZD)
#define ACT_SHIFT -13.81550955796f
#define ROWA 136      // hA leading dim (shorts)
#define ROWB 136      // hB leading dim (shorts)
#define SAMP 64       // samples per k_mlp block (36KB LDS -> 4 blocks/CU)

typedef __bf16 bf16x8 __attribute__((ext_vector_type(8)));
typedef float f32x4 __attribute__((ext_vector_type(4)));
typedef float f32x16 __attribute__((ext_vector_type(16)));

static __device__ inline unsigned short f2bf(float f){
  __hip_bfloat16 h = __float2bfloat16(f);
  unsigned short u; __builtin_memcpy(&u, &h, 2); return u;
}

#if defined(__has_builtin)
#if __has_builtin(__builtin_amdgcn_cvt_pk_bf16_f32)
#define HAVE_PK_BF16 1
#endif
#endif

static __device__ inline unsigned int packbf(float a, float b){
#ifdef HAVE_PK_BF16
  typedef __bf16 bf16v2 __attribute__((ext_vector_type(2)));
  bf16v2 r = __builtin_amdgcn_cvt_pk_bf16_f32(a, b);
  unsigned int u; __builtin_memcpy(&u, &r, 4); return u;
#else
  return (unsigned int)f2bf(a) | ((unsigned int)f2bf(b) << 16);
#endif
}

struct Tri {
  int ix, iy, iz;
  float wx0, wx1, wy0, wy1, wz0, wz1;
};
static __device__ inline Tri tri_setup(float x, float y, float z){
  Tri t;
  float tx = (x+1.f)*0.5f*(float)(GXD-1); tx = fminf(fmaxf(tx,0.f),(float)(GXD-1));
  float ty = (y+1.f)*0.5f*(float)(GYD-1); ty = fminf(fmaxf(ty,0.f),(float)(GYD-1));
  float tz = (z+1.f)*0.5f*(float)(GZD-1); tz = fminf(fmaxf(tz,0.f),(float)(GZD-1));
  t.ix = min((int)tx, GXD-2); t.iy = min((int)ty, GYD-2); t.iz = min((int)tz, GZD-2);
  float fx = tx-t.ix, fy = ty-t.iy, fz = tz-t.iz;
  t.wx0 = 1.f-fx; t.wx1 = fx; t.wy0 = 1.f-fy; t.wy1 = fy; t.wz0 = 1.f-fz; t.wz1 = fz;
  return t;
}

// ---------------- tiny prologue: detect | weights | ray view-term --------------
#define NB_W  184                     // ceil(47104/256)
#define NB_RT (NRAYS/256)             // 32
__global__ __launch_bounds__(256) void k_prep(
    const unsigned int* __restrict__ mw, int* __restrict__ flag,
    const float* __restrict__ W0, const float* __restrict__ W1,
    const float* __restrict__ W2, const float* __restrict__ Wr,
    const float* __restrict__ br,
    unsigned short* __restrict__ wt0, unsigned short* __restrict__ wt1,
    unsigned short* __restrict__ wt2, unsigned short* __restrict__ wtr,
    const float* __restrict__ vd, float* __restrict__ rayterm3)
{
  int b = blockIdx.x;
  if(b == 0){
    unsigned int v = mw[threadIdx.x & 63];
    unsigned long long any = __ballot(v > 1u);
    if(threadIdx.x == 0) *flag = (any != 0ull) ? 1 : 0;   // 1 = byte mask
    return;
  }
  if(b < 1 + NB_W){
    int t = (b - 1)*256 + threadIdx.x;
    if(t < 128*96){
      int n = t/96, k = t%96;
      wt0[t] = f2bf((k < 75) ? W0[k*128 + n] : 0.f);
    } else if(t < 128*96 + 16384){
      int j = t - 128*96; int n = j/128, k = j%128;
      wt1[j] = f2bf(W1[k*128 + n]);
    } else if(t < 128*96 + 32768){
      int j = t - 128*96 - 16384; int n = j/128, k = j%128;
      wt2[j] = f2bf(W2[k*128 + n]);
    } else if(t < 128*96 + 32768 + 16*128){
      int j = t - 128*96 - 32768; int n = j/128, k = j%128;
      wtr[j] = f2bf((n < 3) ? Wr[k*3 + n] : 0.f);
    }
    return;
  }
  // per-ray view term: rayterm3[ray][c] = br[c] + sum_j ve_j * Wr[(128+j)*3+c]
  int ray = (b - 1 - NB_W)*256 + threadIdx.x;
  if(ray >= NRAYS) return;
  float v0 = vd[ray*3+0], v1 = vd[ray*3+1], v2 = vd[ray*3+2];
  float vej[27];
  vej[0] = v0; vej[1] = v1; vej[2] = v2;
  #pragma unroll
  for(int ci = 0; ci < 3; ++ci){
    float xv = (ci == 0) ? v0 : ((ci == 1) ? v1 : v2);
    #pragma unroll
    for(int p = 0; p < 4; ++p){
      float arg = xv * (float)(1 << p);
      vej[3 + ci*4 + p]  = __sinf(arg);
      vej[15 + ci*4 + p] = __cosf(arg);
    }
  }
  float rt0 = br[0], rt1 = br[1], rt2 = br[2];
  #pragma unroll
  for(int j = 0; j < 27; ++j){
    const float* wr = Wr + (128 + j)*3;
    rt0 += vej[j]*wr[0]; rt1 += vej[j]*wr[1]; rt2 += vej[j]*wr[2];
  }
  rayterm3[ray*3+0] = rt0; rayterm3[ray*3+1] = rt1; rayterm3[ray*3+2] = rt2;
}

// ---------------- gather: scattered trilinear, max-occupancy, no LDS -----------
// 4 threads per sample (xy-corners; z in-thread). Reads raw f32 density/k0
// (L3-resident). Writes 32B/sample bf16 record {12 feats, x,y,z, sin(x)} +
// f32 alpha. Latency hidden by TLP (no barriers, no LDS, low VGPR).
__global__ __launch_bounds__(256) void k_gather(
    const float* __restrict__ xyz,
    const float* __restrict__ density, const float* __restrict__ k0,
    const void* __restrict__ mask, const int* __restrict__ flag,
    uint4* __restrict__ feats, float* __restrict__ alphab)
{
  int gid = blockIdx.x*256 + threadIdx.x;
  int smp = gid >> 2, corner = gid & 3;
  float x = xyz[3*smp+0], y = xyz[3*smp+1], z = xyz[3*smp+2];
  Tri t = tri_setup(x, y, z);
  int dx = corner & 1, dy = corner >> 1;
  float wxy = (dx ? t.wx1 : t.wx0) * (dy ? t.wy1 : t.wy0);
  float w0 = wxy*t.wz0, w1 = wxy*t.wz1;
  size_t vox = (size_t)((t.ix+dx)*GYZ + (t.iy+dy)*GZD + t.iz);

  float pd = w0*density[vox] + w1*density[vox+1];
  const float4* v = (const float4*)(k0 + vox*12);
  float4 a0 = v[0], a1 = v[1], a2 = v[2];
  float4 c0 = v[3], c1 = v[4], c2 = v[5];
  float pf[12];
  pf[0] = w0*a0.x + w1*c0.x;  pf[1] = w0*a0.y + w1*c0.y;
  pf[2] = w0*a0.z + w1*c0.z;  pf[3] = w0*a0.w + w1*c0.w;
  pf[4] = w0*a1.x + w1*c1.x;  pf[5] = w0*a1.y + w1*c1.y;
  pf[6] = w0*a1.z + w1*c1.z;  pf[7] = w0*a1.w + w1*c1.w;
  pf[8] = w0*a2.x + w1*c2.x;  pf[9] = w0*a2.y + w1*c2.y;
  pf[10]= w0*a2.z + w1*c2.z;  pf[11]= w0*a2.w + w1*c2.w;

  #pragma unroll
  for(int m2 = 1; m2 < 4; m2 <<= 1){
    pd += __shfl_xor(pd, m2);
    #pragma unroll
    for(int j = 0; j < 12; ++j) pf[j] += __shfl_xor(pf[j], m2);
  }
  if(corner == 0){
    int mx = (int)rintf(x*79.5f + 79.5f); mx = min(max(mx,0), GXD-1);
    int my = (int)rintf(y*79.5f + 79.5f); my = min(max(my,0), GYD-1);
    int mz = (int)rintf(z*63.5f + 63.5f); mz = min(max(mz,0), GZD-1);
    int midx = mx*GYZ + my*GZD + mz;
    bool mm = (*flag) ? (((const unsigned char*)mask)[midx] != 0)
                      : (((const int*)mask)[midx] != 0);
    float e = __expf(pd + ACT_SHIFT);
    float alpha = 1.f - rsqrtf(1.f + e);   // (1+e)^(-0.5), INTERVAL=0.5
    if(!mm) alpha = 0.f;
    alphab[smp] = alpha;
    unsigned int d[8];
    #pragma unroll
    for(int j = 0; j < 6; ++j) d[j] = packbf(pf[2*j], pf[2*j+1]);
    d[6] = packbf(x, y);
    d[7] = packbf(z, __sinf(x));           // col 15 = sin(x * 2^0)
    feats[(size_t)smp*2]   = make_uint4(d[0],d[1],d[2],d[3]);
    feats[(size_t)smp*2+1] = make_uint4(d[4],d[5],d[6],d[7]);
  }
}

// ---------------- MFMA layer (R2-proven): weights prefetched to regs ----------
template<int KDIM, int SROW>
static __device__ __forceinline__ void mfma_layer(const unsigned short* src,
    const bf16x8* wf, f32x16& acc0, f32x16& acc1, int ln, int kh)
{
  constexpr int NS = KDIM/16;
  const unsigned short* abase0 = src + (ln)*SROW + kh*8;
  const unsigned short* abase1 = src + (32 + ln)*SROW + kh*8;
  f32x16 z = {0.f,0.f,0.f,0.f,0.f,0.f,0.f,0.f,0.f,0.f,0.f,0.f,0.f,0.f,0.f,0.f};
  acc0 = z; acc1 = z;
  __builtin_amdgcn_s_setprio(1);
  #pragma unroll
  for(int st = 0; st < NS; ++st){
    bf16x8 a0 = *(const bf16x8*)(abase0 + st*16);
    bf16x8 a1 = *(const bf16x8*)(abase1 + st*16);
    acc0 = __builtin_amdgcn_mfma_f32_32x32x16_bf16(wf[st], a0, acc0, 0, 0, 0);
    acc1 = __builtin_amdgcn_mfma_f32_32x32x16_bf16(wf[st], a1, acc1, 0, 0, 0);
  }
  __builtin_amdgcn_s_setprio(0);
}

template<int NS>
static __device__ __forceinline__ void load_wf(const unsigned short* wbase, bf16x8* wf){
  #pragma unroll
  for(int st = 0; st < NS; ++st) wf[st] = *(const bf16x8*)(wbase + st*16);
}

template<int DROW>
static __device__ __forceinline__ void epilogue(const f32x16& acc0, const f32x16& acc1,
    unsigned short* dst, const float* __restrict__ bias, int tile_n, int ln, int kh)
{
  float4 bv[4];
  #pragma unroll
  for(int g = 0; g < 4; ++g) bv[g] = *(const float4*)(bias + tile_n*32 + g*8 + kh*4);
  #pragma unroll
  for(int rep = 0; rep < 2; ++rep){
    const f32x16& acc = rep ? acc1 : acc0;
    int scol = rep*32 + ln;
    #pragma unroll
    for(int g = 0; g < 4; ++g){
      int n0 = tile_n*32 + g*8 + kh*4;
      unsigned int lo = packbf(fmaxf(acc[4*g+0] + bv[g].x, 0.f), fmaxf(acc[4*g+1] + bv[g].y, 0.f));
      unsigned int hi = packbf(fmaxf(acc[4*g+2] + bv[g].z, 0.f), fmaxf(acc[4*g+3] + bv[g].w, 0.f));
      unsigned long long o = (unsigned long long)lo | ((unsigned long long)hi << 32);
      *(unsigned long long*)(dst + scol*DROW + n0) = o;
    }
  }
}

// ---------------- MLP: coalesced feats + posemb + MFMA chain + head -----------
__global__ __launch_bounds__(256, 4) void k_mlp(const float* __restrict__ xyz,
    const uint4* __restrict__ feats, const float* __restrict__ alphab,
    const int* __restrict__ ray_id,
    const unsigned short* __restrict__ wt0, const unsigned short* __restrict__ wt1,
    const unsigned short* __restrict__ wt2, const unsigned short* __restrict__ wtr,
    const float* __restrict__ b0, const float* __restrict__ b1,
    const float* __restrict__ b2,
    const float* __restrict__ rayterm3, float4* __restrict__ rgba_out)
{
  __shared__ alignas(16) unsigned short hA[SAMP*ROWA];
  __shared__ alignas(16) unsigned short hB[SAMP*ROWB];
  __shared__ float red[SAMP][4];
  __shared__ int ray_s[SAMP];

  int tid = threadIdx.x;
  int lane = tid & 63, wave = tid >> 6;
  int blk = blockIdx.x*SAMP;
  int ln = lane & 31, kh = lane >> 5;

  // layer-0 weight prefetch at entry: latency hides under phase 0
  bf16x8 wf[8];
  load_wf<6>(wt0 + (wave*32 + ln)*96 + kh*8, wf);

  // ---- phase 0: coalesced loads + posemb ------------------------------------
  uint4 fv = make_uint4(0,0,0,0);
  if(tid < 128) fv = feats[(size_t)blk*2 + tid];
  int smp = tid & 63, chunk = 1 + (tid >> 6);   // 1..4
  int i2 = blk + smp;
  float x = xyz[3*i2+0], y = xyz[3*i2+1], z = xyz[3*i2+2];
  float al = 0.f; int rid = 0;
  if(tid < SAMP){ al = alphab[blk + tid]; rid = ray_id[blk + tid]; }

  // posemb cols 16..79: 256 lanes = 64 samples x 4 chunks
  {
    float vv[16];
    #pragma unroll
    for(int j = 0; j < 16; ++j){
      int c = chunk*16 + j;
      float r;
      if(c >= 75) r = 0.f;
      else {
        int q = (c < 45) ? (c-15) : (c-45);
        int ci = q/10, p = q - ci*10;
        float xv = (ci == 0) ? x : ((ci == 1) ? y : z);
        float a = xv * (float)(1 << p);
        r = (c < 45) ? __sinf(a) : __cosf(a);
      }
      vv[j] = r;
    }
    unsigned int d[8];
    #pragma unroll
    for(int j = 0; j < 8; ++j) d[j] = packbf(vv[2*j], vv[2*j+1]);
    uint4* p = (uint4*)(hA + smp*ROWA + chunk*16);
    p[0] = make_uint4(d[0],d[1],d[2],d[3]);
    p[1] = make_uint4(d[4],d[5],d[6],d[7]);
  }
  // feats -> cols 0..15 (128 threads); zeros -> cols 80..95 (128 threads)
  if(tid < 128){
    *(uint4*)(hA + (tid>>1)*ROWA + (tid&1)*8) = fv;
  } else {
    *(uint4*)(hA + ((tid-128)>>1)*ROWA + 80 + (tid&1)*8) = make_uint4(0,0,0,0);
  }
  if(tid < SAMP) ray_s[tid] = rid;
  __syncthreads();

  f32x16 acc0, acc1;

  // layer 0 (K=96): wf resident; prefetch layer-1 weights under epilogue
  mfma_layer<96, ROWA>(hA, wf, acc0, acc1, ln, kh);
  load_wf<8>(wt1 + (wave*32 + ln)*128 + kh*8, wf);
  epilogue<ROWB>(acc0, acc1, hB, b0, wave, ln, kh);
  __syncthreads();

  // layer 1 (K=128)
  mfma_layer<128, ROWB>(hB, wf, acc0, acc1, ln, kh);
  load_wf<8>(wt2 + (wave*32 + ln)*128 + kh*8, wf);
  epilogue<ROWA>(acc0, acc1, hA, b1, wave, ln, kh);
  __syncthreads();

  // layer 2 (K=128); prefetch head weights under epilogue
  int col = lane & 15, q4 = lane >> 4;
  mfma_layer<128, ROWA>(hA, wf, acc0, acc1, ln, kh);
  bf16x8 hw[4];
  {
    const unsigned short* wr = wtr + col*128 + q4*8;
    #pragma unroll
    for(int ks = 0; ks < 4; ++ks) hw[ks] = *(const bf16x8*)(wr + ks*32);
  }
  epilogue<ROWB>(acc0, acc1, hB, b2, wave, ln, kh);
  __syncthreads();

  // rgb head: 16x16x32 MFMA, K=128, 4 m-tiles = 4 waves; + per-ray view term
  {
    int mt = wave;
    f32x4 acc = {0.f, 0.f, 0.f, 0.f};
    const unsigned short* arow = hB + (mt*16 + col)*ROWB + q4*8;
    __builtin_amdgcn_s_setprio(1);
    #pragma unroll
    for(int ks = 0; ks < 4; ++ks){
      bf16x8 af = *(const bf16x8*)(arow + ks*32);
      acc = __builtin_amdgcn_mfma_f32_16x16x32_bf16(af, hw[ks], acc, 0, 0, 0);
    }
    __builtin_amdgcn_s_setprio(0);
    if(col < 3){
      #pragma unroll
      for(int r = 0; r < 4; ++r){
        int sl = mt*16 + q4*4 + r;
        float v = acc[r] + rayterm3[ray_s[sl]*3 + col];
        red[sl][col] = __fdividef(1.f, 1.f + __expf(-v));
      }
    }
  }
  __syncthreads();

  // coalesced rgba store (alpha from k_gather rides in .w)
  if(tid < SAMP){
    rgba_out[blk + tid] = make_float4(red[tid][0], red[tid][1], red[tid][2], al);
  }
}

// ---------------- per-ray: alpha scan + weighted composite in one pass ---------
__global__ __launch_bounds__(256) void k_comp2(const int* __restrict__ ray_id,
    const float4* __restrict__ rgba, float* __restrict__ out)
{
  int r = blockIdx.x*4 + (threadIdx.x >> 6);   // grid = NRAYS/4 blocks
  int lane = threadIdx.x & 63;
  int lo = 0, hi = M_SAMPLES;
  while(lo < hi){ int mid = (lo+hi) >> 1; if(ray_id[mid] < r) lo = mid+1; else hi = mid; }
  int s = lo;
  int lo2 = s, hi2 = M_SAMPLES;
  while(lo2 < hi2){ int mid = (lo2+hi2) >> 1; if(ray_id[mid] < r+1) lo2 = mid+1; else hi2 = mid; }
  int e = lo2;

  float carry = 1.f;
  float ar = 0.f, ag = 0.f, ab = 0.f;
  for(int base = s; base < e; base += 64){
    int idx = base + lane;
    float4 c = (idx < e) ? rgba[idx] : make_float4(0.f,0.f,0.f,0.f);
    float a = c.w;
    float incl = 1.f - a;
    #pragma unroll
    for(int d2 = 1; d2 < 64; d2 <<= 1){
      float t = __shfl_up(incl, d2);
      if(lane >= d2) incl *= t;
    }
    float excl = __shfl_up(incl, 1);
    if(lane == 0) excl = 1.f;
    float w = carry * excl * a;
    ar += w*c.x; ag += w*c.y; ab += w*c.z;
    carry *= __shfl(incl, 63);
  }
  #pragma unroll
  for(int m2 = 1; m2 < 64; m2 <<= 1){
    ar += __shfl_xor(ar, m2);
    ag += __shfl_xor(ag, m2);
    ab += __shfl_xor(ab, m2);
  }
  if(lane == 0){
    out[3*r+0] = ar + carry;
    out[3*r+1] = ag + carry;
    out[3*r+2] = ab + carry;
  }
}

// ---------------- host ----------------------------------------------------------
extern "C" void kernel_launch(void* const* d_in, const int* in_sizes, int n_in,
                              void* d_out, int out_size, void* d_ws, size_t ws_size,
                              hipStream_t stream)
{
  const float* xyz      = (const float*)d_in[0];
  const int*   ray_id   = (const int*)  d_in[1];
  const float* viewdirs = (const float*)d_in[2];
  const void*  mask     =               d_in[3];
  const float* density  = (const float*)d_in[4];
  const float* k0       = (const float*)d_in[5];
  const float* W0 = (const float*)d_in[6];  const float* b0 = (const float*)d_in[7];
  const float* W1 = (const float*)d_in[8];  const float* b1 = (const float*)d_in[9];
  const float* W2 = (const float*)d_in[10]; const float* b2 = (const float*)d_in[11];
  const float* Wr = (const float*)d_in[12]; const float* br = (const float*)d_in[13];
  float* out = (float*)d_out;

  char* ws = (char*)d_ws;
  size_t off = 0;
  auto take = [&](size_t nbytes) -> void* {
    void* p = ws + off;
    off = (off + nbytes + 255) & ~(size_t)255;
    return p;
  };
  int*            flag     = (int*)           take(4);
  unsigned short* wt0      = (unsigned short*)take(128*96*2);
  unsigned short* wt1      = (unsigned short*)take(128*128*2);
  unsigned short* wt2      = (unsigned short*)take(128*128*2);
  unsigned short* wtr      = (unsigned short*)take(16*128*2);
  float*          rayterm3 = (float*)         take((size_t)NRAYS*3*4);
  float4*         rgba_ws  = (float4*)        take((size_t)M_SAMPLES*16);
  uint4*          feats    = (uint4*)         take((size_t)M_SAMPLES*32);
  float*          alphab   = (float*)         take((size_t)M_SAMPLES*4);
  (void)ws_size;

  k_prep<<<1 + NB_W + NB_RT, 256, 0, stream>>>(
      (const unsigned int*)mask, flag,
      W0, W1, W2, Wr, br, wt0, wt1, wt2, wtr, viewdirs, rayterm3);
  k_gather<<<M_SAMPLES*4/256, 256, 0, stream>>>(
      xyz, density, k0, mask, flag, feats, alphab);
  k_mlp<<<M_SAMPLES/SAMP, 256, 0, stream>>>(
      xyz, feats, alphab, ray_id, wt0, wt1, wt2, wtr,
      b0, b1, b2, rayterm3, rgba_ws);
  k_comp2<<<NRAYS/4, 256, 0, stream>>>(ray_id, rgba_ws, out);
}

// Round 6
// 442.356 us; speedup vs baseline: 1.0992x; 1.0188x over previous
//
#include <hip/hip_runtime.h>
#include <hip/hip_bf16.h>

#define M_SAMPLES 524288
#define NRAYS 8192
#define GXD 160
#define GYD 160
#define GZD 128
#define GYZ (GYD*GZD)
#define NVOX (GXD*GYD*GZD)
#define ACT_SHIFT -13.81550955796f
#define ROWA 136      // hA leading dim (shorts)
#define ROWB 136      // hB leading dim (shorts)
#define SAMP 64       // samples per k_mlp block (36KB LDS -> 4 blocks/CU)

typedef __bf16 bf16x8 __attribute__((ext_vector_type(8)));
typedef float f32x4 __attribute__((ext_vector_type(4)));
typedef float f32x16 __attribute__((ext_vector_type(16)));
typedef float f32v2 __attribute__((ext_vector_type(2)));

static __device__ inline unsigned short f2bf(float f){
  __hip_bfloat16 h = __float2bfloat16(f);
  unsigned short u; __builtin_memcpy(&u, &h, 2); return u;
}
static __device__ inline float flo(unsigned int u){ return __uint_as_float(u << 16); }
static __device__ inline float fhi(unsigned int u){ return __uint_as_float(u & 0xffff0000u); }

#if defined(__has_builtin)
#if __has_builtin(__builtin_amdgcn_cvt_pk_bf16_f32)
#define HAVE_PK_BF16 1
#endif
#if __has_builtin(__builtin_amdgcn_cvt_pk_f32_fp8) && __has_builtin(__builtin_amdgcn_cvt_pk_fp8_f32)
#define HAVE_FP8 1
#endif
#endif

static __device__ inline unsigned int packbf(float a, float b){
#ifdef HAVE_PK_BF16
  typedef __bf16 bf16v2 __attribute__((ext_vector_type(2)));
  bf16v2 r = __builtin_amdgcn_cvt_pk_bf16_f32(a, b);
  unsigned int u; __builtin_memcpy(&u, &r, 4); return u;
#else
  return (unsigned int)f2bf(a) | ((unsigned int)f2bf(b) << 16);
#endif
}

struct Tri {
  int ix, iy, iz;
  float wx0, wx1, wy0, wy1, wz0, wz1;
};
static __device__ inline Tri tri_setup(float x, float y, float z){
  Tri t;
  float tx = (x+1.f)*0.5f*(float)(GXD-1); tx = fminf(fmaxf(tx,0.f),(float)(GXD-1));
  float ty = (y+1.f)*0.5f*(float)(GYD-1); ty = fminf(fmaxf(ty,0.f),(float)(GYD-1));
  float tz = (z+1.f)*0.5f*(float)(GZD-1); tz = fminf(fmaxf(tz,0.f),(float)(GZD-1));
  t.ix = min((int)tx, GXD-2); t.iy = min((int)ty, GYD-2); t.iz = min((int)tz, GZD-2);
  float fx = tx-t.ix, fy = ty-t.iy, fz = tz-t.iz;
  t.wx0 = 1.f-fx; t.wx1 = fx; t.wy0 = 1.f-fy; t.wy1 = fy; t.wz0 = 1.f-fz; t.wz1 = fz;
  return t;
}

// ---------------- prologue: [repack] | detect | weights | ray view-term --------
#define NB_REPACK (NVOX/256)              // 12800
#define NB_W  184                         // ceil(47104/256)
#define NB_RT (NRAYS/256)                 // 32
__global__ __launch_bounds__(256) void k_prep(int do_repack,
    const float* __restrict__ density, const float* __restrict__ k0,
    uint4* __restrict__ packed,
    const unsigned int* __restrict__ mw, int* __restrict__ flag,
    const float* __restrict__ W0, const float* __restrict__ W1,
    const float* __restrict__ W2, const float* __restrict__ Wr,
    const float* __restrict__ br,
    unsigned short* __restrict__ wt0, unsigned short* __restrict__ wt1,
    unsigned short* __restrict__ wt2, unsigned short* __restrict__ wtr,
    const float* __restrict__ vd, float* __restrict__ rayterm3)
{
  int b = blockIdx.x;
  if(do_repack){
    if(b < NB_REPACK){
      int v = b*256 + threadIdx.x;
      const float4* kp = (const float4*)(k0 + (size_t)v*12);
      float4 a = kp[0], bb = kp[1], c = kp[2];
#ifdef HAVE_FP8
      uint4 o;
      o.x = __float_as_uint(density[v]);
      int w;
      w = __builtin_amdgcn_cvt_pk_fp8_f32(a.x, a.y, 0, false);
      w = __builtin_amdgcn_cvt_pk_fp8_f32(a.z, a.w, w, true);
      o.y = (unsigned int)w;
      w = __builtin_amdgcn_cvt_pk_fp8_f32(bb.x, bb.y, 0, false);
      w = __builtin_amdgcn_cvt_pk_fp8_f32(bb.z, bb.w, w, true);
      o.z = (unsigned int)w;
      w = __builtin_amdgcn_cvt_pk_fp8_f32(c.x, c.y, 0, false);
      w = __builtin_amdgcn_cvt_pk_fp8_f32(c.z, c.w, w, true);
      o.w = (unsigned int)w;
      packed[v] = o;
#else
      uint4 o0, o1;
      o0.x = __float_as_uint(density[v]);
      o0.y = packbf(a.x, a.y); o0.z = packbf(a.z, a.w); o0.w = packbf(bb.x, bb.y);
      o1.x = packbf(bb.z, bb.w); o1.y = packbf(c.x, c.y); o1.z = packbf(c.z, c.w);
      o1.w = 0;
      packed[(size_t)v*2]   = o0;
      packed[(size_t)v*2+1] = o1;
#endif
      return;
    }
    b -= NB_REPACK;
  }
  if(b == 0){
    unsigned int v = mw[threadIdx.x & 63];
    unsigned long long any = __ballot(v > 1u);
    if(threadIdx.x == 0) *flag = (any != 0ull) ? 1 : 0;   // 1 = byte mask
    return;
  }
  if(b < 1 + NB_W){
    int t = (b - 1)*256 + threadIdx.x;
    if(t < 128*96){
      int n = t/96, k = t%96;
      wt0[t] = f2bf((k < 75) ? W0[k*128 + n] : 0.f);
    } else if(t < 128*96 + 16384){
      int j = t - 128*96; int n = j/128, k = j%128;
      wt1[j] = f2bf(W1[k*128 + n]);
    } else if(t < 128*96 + 32768){
      int j = t - 128*96 - 16384; int n = j/128, k = j%128;
      wt2[j] = f2bf(W2[k*128 + n]);
    } else if(t < 128*96 + 32768 + 16*128){
      int j = t - 128*96 - 32768; int n = j/128, k = j%128;
      wtr[j] = f2bf((n < 3) ? Wr[k*3 + n] : 0.f);
    }
    return;
  }
  // per-ray view term: rayterm3[ray][c] = br[c] + sum_j ve_j * Wr[(128+j)*3+c]
  int ray = (b - 1 - NB_W)*256 + threadIdx.x;
  if(ray >= NRAYS) return;
  float v0 = vd[ray*3+0], v1 = vd[ray*3+1], v2 = vd[ray*3+2];
  float vej[27];
  vej[0] = v0; vej[1] = v1; vej[2] = v2;
  #pragma unroll
  for(int ci = 0; ci < 3; ++ci){
    float xv = (ci == 0) ? v0 : ((ci == 1) ? v1 : v2);
    #pragma unroll
    for(int p = 0; p < 4; ++p){
      float arg = xv * (float)(1 << p);
      vej[3 + ci*4 + p]  = __sinf(arg);
      vej[15 + ci*4 + p] = __cosf(arg);
    }
  }
  float rt0 = br[0], rt1 = br[1], rt2 = br[2];
  #pragma unroll
  for(int j = 0; j < 27; ++j){
    const float* wr = Wr + (128 + j)*3;
    rt0 += vej[j]*wr[0]; rt1 += vej[j]*wr[1]; rt2 += vej[j]*wr[2];
  }
  rayterm3[ray*3+0] = rt0; rayterm3[ray*3+1] = rt1; rayterm3[ray*3+2] = rt2;
}

// ---------------- gather: scattered trilinear from PACKED voxels ---------------
// 4 threads per sample (xy-corners; z in-thread). Packed record = 16B/voxel
// (f32 density + 12 fp8 feats) -> scattered footprint 52MB, ~64B line/corner.
// No LDS, no barriers -> latency hidden by TLP.
template<int PACKED>
__global__ __launch_bounds__(256) void k_gather(
    const float* __restrict__ xyz,
    const uint4* __restrict__ packed,
    const float* __restrict__ density, const float* __restrict__ k0,
    const void* __restrict__ mask, const int* __restrict__ flag,
    uint4* __restrict__ feats, float* __restrict__ alphab)
{
  int gid = blockIdx.x*256 + threadIdx.x;
  int smp = gid >> 2, corner = gid & 3;
  float x = xyz[3*smp+0], y = xyz[3*smp+1], z = xyz[3*smp+2];
  Tri t = tri_setup(x, y, z);
  int dx = corner & 1, dy = corner >> 1;
  float wxy = (dx ? t.wx1 : t.wx0) * (dy ? t.wy1 : t.wy0);
  float w0 = wxy*t.wz0, w1 = wxy*t.wz1;
  size_t vox = (size_t)((t.ix+dx)*GYZ + (t.iy+dy)*GZD + t.iz);

  float pd;
  float pf[12];
#ifdef HAVE_FP8
  if(PACKED){
    uint4 q0 = packed[vox], q1 = packed[vox+1];
    pd = w0*__uint_as_float(q0.x) + w1*__uint_as_float(q1.x);
    f32v2 a, b;
    a = __builtin_amdgcn_cvt_pk_f32_fp8((int)q0.y, false);
    b = __builtin_amdgcn_cvt_pk_f32_fp8((int)q1.y, false);
    pf[0] = w0*a.x + w1*b.x;  pf[1] = w0*a.y + w1*b.y;
    a = __builtin_amdgcn_cvt_pk_f32_fp8((int)q0.y, true);
    b = __builtin_amdgcn_cvt_pk_f32_fp8((int)q1.y, true);
    pf[2] = w0*a.x + w1*b.x;  pf[3] = w0*a.y + w1*b.y;
    a = __builtin_amdgcn_cvt_pk_f32_fp8((int)q0.z, false);
    b = __builtin_amdgcn_cvt_pk_f32_fp8((int)q1.z, false);
    pf[4] = w0*a.x + w1*b.x;  pf[5] = w0*a.y + w1*b.y;
    a = __builtin_amdgcn_cvt_pk_f32_fp8((int)q0.z, true);
    b = __builtin_amdgcn_cvt_pk_f32_fp8((int)q1.z, true);
    pf[6] = w0*a.x + w1*b.x;  pf[7] = w0*a.y + w1*b.y;
    a = __builtin_amdgcn_cvt_pk_f32_fp8((int)q0.w, false);
    b = __builtin_amdgcn_cvt_pk_f32_fp8((int)q1.w, false);
    pf[8] = w0*a.x + w1*b.x;  pf[9] = w0*a.y + w1*b.y;
    a = __builtin_amdgcn_cvt_pk_f32_fp8((int)q0.w, true);
    b = __builtin_amdgcn_cvt_pk_f32_fp8((int)q1.w, true);
    pf[10]= w0*a.x + w1*b.x;  pf[11]= w0*a.y + w1*b.y;
  }
#else
  if(PACKED){
    const uint4* pv = packed + vox*2;
    uint4 q0 = pv[0], q1 = pv[1], q2 = pv[2], q3 = pv[3];
    pd = w0*__uint_as_float(q0.x) + w1*__uint_as_float(q2.x);
    pf[0]  = w0*flo(q0.y) + w1*flo(q2.y);  pf[1]  = w0*fhi(q0.y) + w1*fhi(q2.y);
    pf[2]  = w0*flo(q0.z) + w1*flo(q2.z);  pf[3]  = w0*fhi(q0.z) + w1*fhi(q2.z);
    pf[4]  = w0*flo(q0.w) + w1*flo(q2.w);  pf[5]  = w0*fhi(q0.w) + w1*fhi(q2.w);
    pf[6]  = w0*flo(q1.x) + w1*flo(q3.x);  pf[7]  = w0*fhi(q1.x) + w1*fhi(q3.x);
    pf[8]  = w0*flo(q1.y) + w1*flo(q3.y);  pf[9]  = w0*fhi(q1.y) + w1*fhi(q3.y);
    pf[10] = w0*flo(q1.z) + w1*flo(q3.z);  pf[11] = w0*fhi(q1.z) + w1*fhi(q3.z);
  }
#endif
  if(!PACKED){
    pd = w0*density[vox] + w1*density[vox+1];
    const float4* v = (const float4*)(k0 + vox*12);
    float4 a0 = v[0], a1 = v[1], a2 = v[2];
    float4 c0 = v[3], c1 = v[4], c2 = v[5];
    pf[0] = w0*a0.x + w1*c0.x;  pf[1] = w0*a0.y + w1*c0.y;
    pf[2] = w0*a0.z + w1*c0.z;  pf[3] = w0*a0.w + w1*c0.w;
    pf[4] = w0*a1.x + w1*c1.x;  pf[5] = w0*a1.y + w1*c1.y;
    pf[6] = w0*a1.z + w1*c1.z;  pf[7] = w0*a1.w + w1*c1.w;
    pf[8] = w0*a2.x + w1*c2.x;  pf[9] = w0*a2.y + w1*c2.y;
    pf[10]= w0*a2.z + w1*c2.z;  pf[11]= w0*a2.w + w1*c2.w;
  }

  #pragma unroll
  for(int m2 = 1; m2 < 4; m2 <<= 1){
    pd += __shfl_xor(pd, m2);
    #pragma unroll
    for(int j = 0; j < 12; ++j) pf[j] += __shfl_xor(pf[j], m2);
  }
  if(corner == 0){
    int mx = (int)rintf(x*79.5f + 79.5f); mx = min(max(mx,0), GXD-1);
    int my = (int)rintf(y*79.5f + 79.5f); my = min(max(my,0), GYD-1);
    int mz = (int)rintf(z*63.5f + 63.5f); mz = min(max(mz,0), GZD-1);
    int midx = mx*GYZ + my*GZD + mz;
    bool mm = (*flag) ? (((const unsigned char*)mask)[midx] != 0)
                      : (((const int*)mask)[midx] != 0);
    float e = __expf(pd + ACT_SHIFT);
    float alpha = 1.f - rsqrtf(1.f + e);   // (1+e)^(-0.5), INTERVAL=0.5
    if(!mm) alpha = 0.f;
    alphab[smp] = alpha;
    unsigned int d[8];
    #pragma unroll
    for(int j = 0; j < 6; ++j) d[j] = packbf(pf[2*j], pf[2*j+1]);
    d[6] = packbf(x, y);
    d[7] = packbf(z, __sinf(x));           // col 15 = sin(x * 2^0)
    feats[(size_t)smp*2]   = make_uint4(d[0],d[1],d[2],d[3]);
    feats[(size_t)smp*2+1] = make_uint4(d[4],d[5],d[6],d[7]);
  }
}

// ---------------- MFMA layer (R2-proven): weights prefetched to regs ----------
template<int KDIM, int SROW>
static __device__ __forceinline__ void mfma_layer(const unsigned short* src,
    const bf16x8* wf, f32x16& acc0, f32x16& acc1, int ln, int kh)
{
  constexpr int NS = KDIM/16;
  const unsigned short* abase0 = src + (ln)*SROW + kh*8;
  const unsigned short* abase1 = src + (32 + ln)*SROW + kh*8;
  f32x16 z = {0.f,0.f,0.f,0.f,0.f,0.f,0.f,0.f,0.f,0.f,0.f,0.f,0.f,0.f,0.f,0.f};
  acc0 = z; acc1 = z;
  __builtin_amdgcn_s_setprio(1);
  #pragma unroll
  for(int st = 0; st < NS; ++st){
    bf16x8 a0 = *(const bf16x8*)(abase0 + st*16);
    bf16x8 a1 = *(const bf16x8*)(abase1 + st*16);
    acc0 = __builtin_amdgcn_mfma_f32_32x32x16_bf16(wf[st], a0, acc0, 0, 0, 0);
    acc1 = __builtin_amdgcn_mfma_f32_32x32x16_bf16(wf[st], a1, acc1, 0, 0, 0);
  }
  __builtin_amdgcn_s_setprio(0);
}

template<int NS>
static __device__ __forceinline__ void load_wf(const unsigned short* wbase, bf16x8* wf){
  #pragma unroll
  for(int st = 0; st < NS; ++st) wf[st] = *(const bf16x8*)(wbase + st*16);
}

template<int DROW>
static __device__ __forceinline__ void epilogue(const f32x16& acc0, const f32x16& acc1,
    unsigned short* dst, const float* __restrict__ bias, int tile_n, int ln, int kh)
{
  float4 bv[4];
  #pragma unroll
  for(int g = 0; g < 4; ++g) bv[g] = *(const float4*)(bias + tile_n*32 + g*8 + kh*4);
  #pragma unroll
  for(int rep = 0; rep < 2; ++rep){
    const f32x16& acc = rep ? acc1 : acc0;
    int scol = rep*32 + ln;
    #pragma unroll
    for(int g = 0; g < 4; ++g){
      int n0 = tile_n*32 + g*8 + kh*4;
      unsigned int lo = packbf(fmaxf(acc[4*g+0] + bv[g].x, 0.f), fmaxf(acc[4*g+1] + bv[g].y, 0.f));
      unsigned int hi = packbf(fmaxf(acc[4*g+2] + bv[g].z, 0.f), fmaxf(acc[4*g+3] + bv[g].w, 0.f));
      unsigned long long o = (unsigned long long)lo | ((unsigned long long)hi << 32);
      *(unsigned long long*)(dst + scol*DROW + n0) = o;
    }
  }
}

// ---------------- MLP: coalesced feats + posemb + MFMA chain + head -----------
__global__ __launch_bounds__(256, 4) void k_mlp(const float* __restrict__ xyz,
    const uint4* __restrict__ feats, const float* __restrict__ alphab,
    const int* __restrict__ ray_id,
    const unsigned short* __restrict__ wt0, const unsigned short* __restrict__ wt1,
    const unsigned short* __restrict__ wt2, const unsigned short* __restrict__ wtr,
    const float* __restrict__ b0, const float* __restrict__ b1,
    const float* __restrict__ b2,
    const float* __restrict__ rayterm3, float4* __restrict__ rgba_out)
{
  __shared__ alignas(16) unsigned short hA[SAMP*ROWA];
  __shared__ alignas(16) unsigned short hB[SAMP*ROWB];
  __shared__ float red[SAMP][4];
  __shared__ int ray_s[SAMP];

  int tid = threadIdx.x;
  int lane = tid & 63, wave = tid >> 6;
  int blk = blockIdx.x*SAMP;
  int ln = lane & 31, kh = lane >> 5;

  // layer-0 weight prefetch at entry: latency hides under phase 0
  bf16x8 wf[8];
  load_wf<6>(wt0 + (wave*32 + ln)*96 + kh*8, wf);

  // ---- phase 0: coalesced loads + posemb ------------------------------------
  uint4 fv = make_uint4(0,0,0,0);
  if(tid < 128) fv = feats[(size_t)blk*2 + tid];
  int smp = tid & 63, chunk = 1 + (tid >> 6);   // 1..4
  int i2 = blk + smp;
  float x = xyz[3*i2+0], y = xyz[3*i2+1], z = xyz[3*i2+2];
  float al = 0.f; int rid = 0;
  if(tid < SAMP){ al = alphab[blk + tid]; rid = ray_id[blk + tid]; }

  // posemb cols 16..79: 256 lanes = 64 samples x 4 chunks
  {
    float vv[16];
    #pragma unroll
    for(int j = 0; j < 16; ++j){
      int c = chunk*16 + j;
      float r;
      if(c >= 75) r = 0.f;
      else {
        int q = (c < 45) ? (c-15) : (c-45);
        int ci = q/10, p = q - ci*10;
        float xv = (ci == 0) ? x : ((ci == 1) ? y : z);
        float a = xv * (float)(1 << p);
        r = (c < 45) ? __sinf(a) : __cosf(a);
      }
      vv[j] = r;
    }
    unsigned int d[8];
    #pragma unroll
    for(int j = 0; j < 8; ++j) d[j] = packbf(vv[2*j], vv[2*j+1]);
    uint4* p = (uint4*)(hA + smp*ROWA + chunk*16);
    p[0] = make_uint4(d[0],d[1],d[2],d[3]);
    p[1] = make_uint4(d[4],d[5],d[6],d[7]);
  }
  // feats -> cols 0..15 (128 threads); zeros -> cols 80..95 (128 threads)
  if(tid < 128){
    *(uint4*)(hA + (tid>>1)*ROWA + (tid&1)*8) = fv;
  } else {
    *(uint4*)(hA + ((tid-128)>>1)*ROWA + 80 + (tid&1)*8) = make_uint4(0,0,0,0);
  }
  if(tid < SAMP) ray_s[tid] = rid;
  __syncthreads();

  f32x16 acc0, acc1;

  // layer 0 (K=96): wf resident; prefetch layer-1 weights under epilogue
  mfma_layer<96, ROWA>(hA, wf, acc0, acc1, ln, kh);
  load_wf<8>(wt1 + (wave*32 + ln)*128 + kh*8, wf);
  epilogue<ROWB>(acc0, acc1, hB, b0, wave, ln, kh);
  __syncthreads();

  // layer 1 (K=128)
  mfma_layer<128, ROWB>(hB, wf, acc0, acc1, ln, kh);
  load_wf<8>(wt2 + (wave*32 + ln)*128 + kh*8, wf);
  epilogue<ROWA>(acc0, acc1, hA, b1, wave, ln, kh);
  __syncthreads();

  // layer 2 (K=128); prefetch head weights under epilogue
  int col = lane & 15, q4 = lane >> 4;
  mfma_layer<128, ROWA>(hA, wf, acc0, acc1, ln, kh);
  bf16x8 hw[4];
  {
    const unsigned short* wr = wtr + col*128 + q4*8;
    #pragma unroll
    for(int ks = 0; ks < 4; ++ks) hw[ks] = *(const bf16x8*)(wr + ks*32);
  }
  epilogue<ROWB>(acc0, acc1, hB, b2, wave, ln, kh);
  __syncthreads();

  // rgb head: 16x16x32 MFMA, K=128, 4 m-tiles = 4 waves; + per-ray view term
  {
    int mt = wave;
    f32x4 acc = {0.f, 0.f, 0.f, 0.f};
    const unsigned short* arow = hB + (mt*16 + col)*ROWB + q4*8;
    __builtin_amdgcn_s_setprio(1);
    #pragma unroll
    for(int ks = 0; ks < 4; ++ks){
      bf16x8 af = *(const bf16x8*)(arow + ks*32);
      acc = __builtin_amdgcn_mfma_f32_16x16x32_bf16(af, hw[ks], acc, 0, 0, 0);
    }
    __builtin_amdgcn_s_setprio(0);
    if(col < 3){
      #pragma unroll
      for(int r = 0; r < 4; ++r){
        int sl = mt*16 + q4*4 + r;
        float v = acc[r] + rayterm3[ray_s[sl]*3 + col];
        red[sl][col] = __fdividef(1.f, 1.f + __expf(-v));
      }
    }
  }
  __syncthreads();

  // coalesced rgba store (alpha from k_gather rides in .w)
  if(tid < SAMP){
    rgba_out[blk + tid] = make_float4(red[tid][0], red[tid][1], red[tid][2], al);
  }
}

// ---------------- per-ray: alpha scan + weighted composite in one pass ---------
__global__ __launch_bounds__(256) void k_comp2(const int* __restrict__ ray_id,
    const float4* __restrict__ rgba, float* __restrict__ out)
{
  int r = blockIdx.x*4 + (threadIdx.x >> 6);   // grid = NRAYS/4 blocks
  int lane = threadIdx.x & 63;
  int lo = 0, hi = M_SAMPLES;
  while(lo < hi){ int mid = (lo+hi) >> 1; if(ray_id[mid] < r) lo = mid+1; else hi = mid; }
  int s = lo;
  int lo2 = s, hi2 = M_SAMPLES;
  while(lo2 < hi2){ int mid = (lo2+hi2) >> 1; if(ray_id[mid] < r+1) lo2 = mid+1; else hi2 = mid; }
  int e = lo2;

  float carry = 1.f;
  float ar = 0.f, ag = 0.f, ab = 0.f;
  for(int base = s; base < e; base += 64){
    int idx = base + lane;
    float4 c = (idx < e) ? rgba[idx] : make_float4(0.f,0.f,0.f,0.f);
    float a = c.w;
    float incl = 1.f - a;
    #pragma unroll
    for(int d2 = 1; d2 < 64; d2 <<= 1){
      float t = __shfl_up(incl, d2);
      if(lane >= d2) incl *= t;
    }
    float excl = __shfl_up(incl, 1);
    if(lane == 0) excl = 1.f;
    float w = carry * excl * a;
    ar += w*c.x; ag += w*c.y; ab += w*c.z;
    carry *= __shfl(incl, 63);
  }
  #pragma unroll
  for(int m2 = 1; m2 < 64; m2 <<= 1){
    ar += __shfl_xor(ar, m2);
    ag += __shfl_xor(ag, m2);
    ab += __shfl_xor(ab, m2);
  }
  if(lane == 0){
    out[3*r+0] = ar + carry;
    out[3*r+1] = ag + carry;
    out[3*r+2] = ab + carry;
  }
}

// ---------------- host ----------------------------------------------------------
extern "C" void kernel_launch(void* const* d_in, const int* in_sizes, int n_in,
                              void* d_out, int out_size, void* d_ws, size_t ws_size,
                              hipStream_t stream)
{
  const float* xyz      = (const float*)d_in[0];
  const int*   ray_id   = (const int*)  d_in[1];
  const float* viewdirs = (const float*)d_in[2];
  const void*  mask     =               d_in[3];
  const float* density  = (const float*)d_in[4];
  const float* k0       = (const float*)d_in[5];
  const float* W0 = (const float*)d_in[6];  const float* b0 = (const float*)d_in[7];
  const float* W1 = (const float*)d_in[8];  const float* b1 = (const float*)d_in[9];
  const float* W2 = (const float*)d_in[10]; const float* b2 = (const float*)d_in[11];
  const float* Wr = (const float*)d_in[12]; const float* br = (const float*)d_in[13];
  float* out = (float*)d_out;

  char* ws = (char*)d_ws;
  size_t off = 0;
  auto take = [&](size_t nbytes) -> void* {
    void* p = ws + off;
    off = (off + nbytes + 255) & ~(size_t)255;
    return p;
  };
  int*            flag     = (int*)           take(4);
  unsigned short* wt0      = (unsigned short*)take(128*96*2);
  unsigned short* wt1      = (unsigned short*)take(128*128*2);
  unsigned short* wt2      = (unsigned short*)take(128*128*2);
  unsigned short* wtr      = (unsigned short*)take(16*128*2);
  float*          rayterm3 = (float*)         take((size_t)NRAYS*3*4);
  float4*         rgba_ws  = (float4*)        take((size_t)M_SAMPLES*16);
  uint4*          feats    = (uint4*)         take((size_t)M_SAMPLES*32);
  float*          alphab   = (float*)         take((size_t)M_SAMPLES*4);
#ifdef HAVE_FP8
  uint4*          packed   = (uint4*)         take((size_t)NVOX*16);
#else
  uint4*          packed   = (uint4*)         take((size_t)NVOX*32);
#endif
  int use_packed = (ws_size >= off) ? 1 : 0;

  k_prep<<<(use_packed ? NB_REPACK : 0) + 1 + NB_W + NB_RT, 256, 0, stream>>>(
      use_packed, density, k0, packed, (const unsigned int*)mask, flag,
      W0, W1, W2, Wr, br, wt0, wt1, wt2, wtr, viewdirs, rayterm3);
  if(use_packed){
    k_gather<1><<<M_SAMPLES*4/256, 256, 0, stream>>>(
        xyz, packed, density, k0, mask, flag, feats, alphab);
  } else {
    k_gather<0><<<M_SAMPLES*4/256, 256, 0, stream>>>(
        xyz, packed, density, k0, mask, flag, feats, alphab);
  }
  k_mlp<<<M_SAMPLES/SAMP, 256, 0, stream>>>(
      xyz, feats, alphab, ray_id, wt0, wt1, wt2, wtr,
      b0, b1, b2, rayterm3, rgba_ws);
  k_comp2<<<NRAYS/4, 256, 0, stream>>>(ray_id, rgba_ws, out);
}

// Round 7
// 410.683 us; speedup vs baseline: 1.1840x; 1.0771x over previous
//
#include <hip/hip_runtime.h>
#include <hip/hip_bf16.h>

#define M_SAMPLES 524288
#define NRAYS 8192
#define GXD 160
#define GYD 160
#define GZD 128
#define GYZ (GYD*GZD)
#define NVOX (GXD*GYD*GZD)
#define ACT_SHIFT -13.81550955796f
#define ROWA 136      // hA leading dim (shorts)
#define ROWB 136      // hB leading dim (shorts)
#define SAMP 64       // samples per k_mlp block (36KB LDS -> 4 blocks/CU)

typedef __bf16 bf16x8 __attribute__((ext_vector_type(8)));
typedef float f32x4 __attribute__((ext_vector_type(4)));
typedef float f32x16 __attribute__((ext_vector_type(16)));
typedef float f32v2 __attribute__((ext_vector_type(2)));

static __device__ inline unsigned short f2bf(float f){
  __hip_bfloat16 h = __float2bfloat16(f);
  unsigned short u; __builtin_memcpy(&u, &h, 2); return u;
}
static __device__ inline float flo(unsigned int u){ return __uint_as_float(u << 16); }
static __device__ inline float fhi(unsigned int u){ return __uint_as_float(u & 0xffff0000u); }

#if defined(__has_builtin)
#if __has_builtin(__builtin_amdgcn_cvt_pk_bf16_f32)
#define HAVE_PK_BF16 1
#endif
#if __has_builtin(__builtin_amdgcn_cvt_pk_f32_fp8) && __has_builtin(__builtin_amdgcn_cvt_pk_fp8_f32)
#define HAVE_FP8 1
#endif
#endif

static __device__ inline unsigned int packbf(float a, float b){
#ifdef HAVE_PK_BF16
  typedef __bf16 bf16v2 __attribute__((ext_vector_type(2)));
  bf16v2 r = __builtin_amdgcn_cvt_pk_bf16_f32(a, b);
  unsigned int u; __builtin_memcpy(&u, &r, 4); return u;
#else
  return (unsigned int)f2bf(a) | ((unsigned int)f2bf(b) << 16);
#endif
}

struct Tri {
  int ix, iy, iz;
  float wx0, wx1, wy0, wy1, wz0, wz1;
};
static __device__ inline Tri tri_setup(float x, float y, float z){
  Tri t;
  float tx = (x+1.f)*0.5f*(float)(GXD-1); tx = fminf(fmaxf(tx,0.f),(float)(GXD-1));
  float ty = (y+1.f)*0.5f*(float)(GYD-1); ty = fminf(fmaxf(ty,0.f),(float)(GYD-1));
  float tz = (z+1.f)*0.5f*(float)(GZD-1); tz = fminf(fmaxf(tz,0.f),(float)(GZD-1));
  t.ix = min((int)tx, GXD-2); t.iy = min((int)ty, GYD-2); t.iz = min((int)tz, GZD-2);
  float fx = tx-t.ix, fy = ty-t.iy, fz = tz-t.iz;
  t.wx0 = 1.f-fx; t.wx1 = fx; t.wy0 = 1.f-fy; t.wy1 = fy; t.wz0 = 1.f-fz; t.wz1 = fz;
  return t;
}

// ---------------- merged prologue: repack | detect | weights | ray view-term ---
#define NB_REPACK (NVOX/256)              // 12800
#define NB_W      184                     // ceil(47104/256)
#define NB_RT     (NRAYS/256)             // 32
__global__ __launch_bounds__(256) void k_prep(
    const float* __restrict__ density, const float* __restrict__ k0,
    uint4* __restrict__ packed,
    const unsigned int* __restrict__ mw, int* __restrict__ flag,
    const float* __restrict__ W0, const float* __restrict__ W1,
    const float* __restrict__ W2, const float* __restrict__ Wr,
    const float* __restrict__ br,
    unsigned short* __restrict__ wt0, unsigned short* __restrict__ wt1,
    unsigned short* __restrict__ wt2, unsigned short* __restrict__ wtr,
    const float* __restrict__ vd, float* __restrict__ rayterm3)
{
  int b = blockIdx.x;
  if(b < NB_REPACK){
    int v = b*256 + threadIdx.x;
    const float4* kp = (const float4*)(k0 + (size_t)v*12);
    float4 a = kp[0], bb = kp[1], c = kp[2];
#ifdef HAVE_FP8
    uint4 o;
    o.x = __float_as_uint(density[v]);
    int w;
    w = __builtin_amdgcn_cvt_pk_fp8_f32(a.x, a.y, 0, false);
    w = __builtin_amdgcn_cvt_pk_fp8_f32(a.z, a.w, w, true);
    o.y = (unsigned int)w;
    w = __builtin_amdgcn_cvt_pk_fp8_f32(bb.x, bb.y, 0, false);
    w = __builtin_amdgcn_cvt_pk_fp8_f32(bb.z, bb.w, w, true);
    o.z = (unsigned int)w;
    w = __builtin_amdgcn_cvt_pk_fp8_f32(c.x, c.y, 0, false);
    w = __builtin_amdgcn_cvt_pk_fp8_f32(c.z, c.w, w, true);
    o.w = (unsigned int)w;
    packed[v] = o;
#else
    uint4 o0, o1;
    o0.x = __float_as_uint(density[v]);
    o0.y = packbf(a.x, a.y); o0.z = packbf(a.z, a.w); o0.w = packbf(bb.x, bb.y);
    o1.x = packbf(bb.z, bb.w); o1.y = packbf(c.x, c.y); o1.z = packbf(c.z, c.w);
    o1.w = 0;
    packed[(size_t)v*2]   = o0;
    packed[(size_t)v*2+1] = o1;
#endif
    return;
  }
  if(b == NB_REPACK){
    unsigned int v = mw[threadIdx.x & 63];
    unsigned long long any = __ballot(v > 1u);
    if(threadIdx.x == 0) *flag = (any != 0ull) ? 1 : 0;   // 1 = byte mask
    return;
  }
  if(b < NB_REPACK + 1 + NB_W){
    int t = (b - NB_REPACK - 1)*256 + threadIdx.x;
    if(t < 128*96){
      int n = t/96, k = t%96;
      wt0[t] = f2bf((k < 75) ? W0[k*128 + n] : 0.f);
    } else if(t < 128*96 + 16384){
      int j = t - 128*96; int n = j/128, k = j%128;
      wt1[j] = f2bf(W1[k*128 + n]);
    } else if(t < 128*96 + 32768){
      int j = t - 128*96 - 16384; int n = j/128, k = j%128;
      wt2[j] = f2bf(W2[k*128 + n]);
    } else if(t < 128*96 + 32768 + 16*128){
      int j = t - 128*96 - 32768; int n = j/128, k = j%128;
      wtr[j] = f2bf((n < 3) ? Wr[k*3 + n] : 0.f);
    }
    return;
  }
  // per-ray view term: rayterm3[ray][c] = br[c] + sum_j ve_j * Wr[(128+j)*3+c]
  int ray = (b - NB_REPACK - 1 - NB_W)*256 + threadIdx.x;
  if(ray >= NRAYS) return;
  float v0 = vd[ray*3+0], v1 = vd[ray*3+1], v2 = vd[ray*3+2];
  float vej[27];
  vej[0] = v0; vej[1] = v1; vej[2] = v2;
  #pragma unroll
  for(int ci = 0; ci < 3; ++ci){
    float xv = (ci == 0) ? v0 : ((ci == 1) ? v1 : v2);
    #pragma unroll
    for(int p = 0; p < 4; ++p){
      float arg = xv * (float)(1 << p);
      vej[3 + ci*4 + p]  = __sinf(arg);
      vej[15 + ci*4 + p] = __cosf(arg);
    }
  }
  float rt0 = br[0], rt1 = br[1], rt2 = br[2];
  #pragma unroll
  for(int j = 0; j < 27; ++j){
    const float* wr = Wr + (128 + j)*3;
    rt0 += vej[j]*wr[0]; rt1 += vej[j]*wr[1]; rt2 += vej[j]*wr[2];
  }
  rayterm3[ray*3+0] = rt0; rayterm3[ray*3+1] = rt1; rayterm3[ray*3+2] = rt2;
}

// ---------------- MFMA layer: acc initialized with bias (saves epilogue adds) --
template<int KDIM, int SROW>
static __device__ __forceinline__ void mfma_layer(const unsigned short* src,
    const bf16x8* wf, const float* __restrict__ bias, int tile_n,
    f32x16& acc0, f32x16& acc1, int ln, int kh)
{
  constexpr int NS = KDIM/16;
  const unsigned short* abase0 = src + (ln)*SROW + kh*8;
  const unsigned short* abase1 = src + (32 + ln)*SROW + kh*8;
  #pragma unroll
  for(int g = 0; g < 4; ++g){
    float4 bv = *(const float4*)(bias + tile_n*32 + g*8 + kh*4);
    acc0[4*g+0] = bv.x; acc0[4*g+1] = bv.y; acc0[4*g+2] = bv.z; acc0[4*g+3] = bv.w;
  }
  acc1 = acc0;
  __builtin_amdgcn_s_setprio(1);
  #pragma unroll
  for(int st = 0; st < NS; ++st){
    bf16x8 a0 = *(const bf16x8*)(abase0 + st*16);
    bf16x8 a1 = *(const bf16x8*)(abase1 + st*16);
    acc0 = __builtin_amdgcn_mfma_f32_32x32x16_bf16(wf[st], a0, acc0, 0, 0, 0);
    acc1 = __builtin_amdgcn_mfma_f32_32x32x16_bf16(wf[st], a1, acc1, 0, 0, 0);
  }
  __builtin_amdgcn_s_setprio(0);
}

template<int NS>
static __device__ __forceinline__ void load_wf(const unsigned short* wbase, bf16x8* wf){
  #pragma unroll
  for(int st = 0; st < NS; ++st) wf[st] = *(const bf16x8*)(wbase + st*16);
}

// epilogue: ReLU + bf16 pack -> LDS (bias already in acc)
template<int DROW>
static __device__ __forceinline__ void epilogue(const f32x16& acc0, const f32x16& acc1,
    unsigned short* dst, int tile_n, int ln, int kh)
{
  #pragma unroll
  for(int rep = 0; rep < 2; ++rep){
    const f32x16& acc = rep ? acc1 : acc0;
    int scol = rep*32 + ln;
    #pragma unroll
    for(int g = 0; g < 4; ++g){
      int n0 = tile_n*32 + g*8 + kh*4;
      unsigned int lo = packbf(fmaxf(acc[4*g+0], 0.f), fmaxf(acc[4*g+1], 0.f));
      unsigned int hi = packbf(fmaxf(acc[4*g+2], 0.f), fmaxf(acc[4*g+3], 0.f));
      unsigned long long o = (unsigned long long)lo | ((unsigned long long)hi << 32);
      *(unsigned long long*)(dst + scol*DROW + n0) = o;
    }
  }
}

// ---------------- fused: gather+alpha + posemb + MLP + head -> per-sample rgba -
template<int PACKED>
__global__ __launch_bounds__(256, 4) void k_mlp(const float* __restrict__ xyz,
    const uint4* __restrict__ packed,
    const float* __restrict__ density, const float* __restrict__ k0,
    const void* __restrict__ mask, const int* __restrict__ flag,
    const int* __restrict__ ray_id,
    const unsigned short* __restrict__ wt0, const unsigned short* __restrict__ wt1,
    const unsigned short* __restrict__ wt2, const unsigned short* __restrict__ wtr,
    const float* __restrict__ b0, const float* __restrict__ b1,
    const float* __restrict__ b2,
    const float* __restrict__ rayterm3, float4* __restrict__ rgba_out)
{
  __shared__ alignas(16) unsigned short hA[SAMP*ROWA];
  __shared__ alignas(16) unsigned short hB[SAMP*ROWB];
  __shared__ float red[SAMP][4];
  __shared__ int ray_s[SAMP];

  int tid = threadIdx.x;
  int lane = tid & 63, wave = tid >> 6;
  int blk = blockIdx.x*SAMP;
  int ln = lane & 31, kh = lane >> 5;

  // layer-0 weight prefetch at entry: latency hides under phase 0
  bf16x8 wf[8];
  load_wf<6>(wt0 + (wave*32 + ln)*96 + kh*8, wf);

  // ---- phase 0a: gather. 256 lanes = 64 samples x 4 corners (dz in-thread) --
  {
    int smp = tid >> 2, corner = tid & 3;
    int i = blk + smp;
    float x = xyz[3*i+0], y = xyz[3*i+1], z = xyz[3*i+2];
    Tri t = tri_setup(x, y, z);
    int dx = corner & 1, dy = corner >> 1;
    float wxy = (dx ? t.wx1 : t.wx0) * (dy ? t.wy1 : t.wy0);
    float w0 = wxy*t.wz0, w1 = wxy*t.wz1;
    size_t vox = (size_t)((t.ix+dx)*GYZ + (t.iy+dy)*GZD + t.iz);
    float pd;
    float pf[12];
#ifdef HAVE_FP8
    if(PACKED){
      uint4 q0 = packed[vox], q1 = packed[vox+1];
      pd = w0*__uint_as_float(q0.x) + w1*__uint_as_float(q1.x);
      f32v2 a, b;
      a = __builtin_amdgcn_cvt_pk_f32_fp8((int)q0.y, false);
      b = __builtin_amdgcn_cvt_pk_f32_fp8((int)q1.y, false);
      pf[0] = w0*a.x + w1*b.x;  pf[1] = w0*a.y + w1*b.y;
      a = __builtin_amdgcn_cvt_pk_f32_fp8((int)q0.y, true);
      b = __builtin_amdgcn_cvt_pk_f32_fp8((int)q1.y, true);
      pf[2] = w0*a.x + w1*b.x;  pf[3] = w0*a.y + w1*b.y;
      a = __builtin_amdgcn_cvt_pk_f32_fp8((int)q0.z, false);
      b = __builtin_amdgcn_cvt_pk_f32_fp8((int)q1.z, false);
      pf[4] = w0*a.x + w1*b.x;  pf[5] = w0*a.y + w1*b.y;
      a = __builtin_amdgcn_cvt_pk_f32_fp8((int)q0.z, true);
      b = __builtin_amdgcn_cvt_pk_f32_fp8((int)q1.z, true);
      pf[6] = w0*a.x + w1*b.x;  pf[7] = w0*a.y + w1*b.y;
      a = __builtin_amdgcn_cvt_pk_f32_fp8((int)q0.w, false);
      b = __builtin_amdgcn_cvt_pk_f32_fp8((int)q1.w, false);
      pf[8] = w0*a.x + w1*b.x;  pf[9] = w0*a.y + w1*b.y;
      a = __builtin_amdgcn_cvt_pk_f32_fp8((int)q0.w, true);
      b = __builtin_amdgcn_cvt_pk_f32_fp8((int)q1.w, true);
      pf[10]= w0*a.x + w1*b.x;  pf[11]= w0*a.y + w1*b.y;
    }
#else
    if(PACKED){
      const uint4* pv = packed + vox*2;
      uint4 q0 = pv[0], q1 = pv[1], q2 = pv[2], q3 = pv[3];
      pd = w0*__uint_as_float(q0.x) + w1*__uint_as_float(q2.x);
      pf[0]  = w0*flo(q0.y) + w1*flo(q2.y);  pf[1]  = w0*fhi(q0.y) + w1*fhi(q2.y);
      pf[2]  = w0*flo(q0.z) + w1*flo(q2.z);  pf[3]  = w0*fhi(q0.z) + w1*fhi(q2.z);
      pf[4]  = w0*flo(q0.w) + w1*flo(q2.w);  pf[5]  = w0*fhi(q0.w) + w1*fhi(q2.w);
      pf[6]  = w0*flo(q1.x) + w1*flo(q3.x);  pf[7]  = w0*fhi(q1.x) + w1*fhi(q3.x);
      pf[8]  = w0*flo(q1.y) + w1*flo(q3.y);  pf[9]  = w0*fhi(q1.y) + w1*fhi(q3.y);
      pf[10] = w0*flo(q1.z) + w1*flo(q3.z);  pf[11] = w0*fhi(q1.z) + w1*fhi(q3.z);
    }
#endif
    if(!PACKED){
      pd = w0*density[vox] + w1*density[vox+1];
      const float4* v = (const float4*)(k0 + vox*12);
      float4 a0 = v[0], a1 = v[1], a2 = v[2];
      float4 c0 = v[3], c1 = v[4], c2 = v[5];
      pf[0] = w0*a0.x + w1*c0.x;  pf[1] = w0*a0.y + w1*c0.y;
      pf[2] = w0*a0.z + w1*c0.z;  pf[3] = w0*a0.w + w1*c0.w;
      pf[4] = w0*a1.x + w1*c1.x;  pf[5] = w0*a1.y + w1*c1.y;
      pf[6] = w0*a1.z + w1*c1.z;  pf[7] = w0*a1.w + w1*c1.w;
      pf[8] = w0*a2.x + w1*c2.x;  pf[9] = w0*a2.y + w1*c2.y;
      pf[10]= w0*a2.z + w1*c2.z;  pf[11]= w0*a2.w + w1*c2.w;
    }
    #pragma unroll
    for(int m2 = 1; m2 < 4; m2 <<= 1){
      pd += __shfl_xor(pd, m2);
      #pragma unroll
      for(int j = 0; j < 12; ++j) pf[j] += __shfl_xor(pf[j], m2);
    }
    if(corner == 0){
      int mx = (int)rintf(x*79.5f + 79.5f); mx = min(max(mx,0), GXD-1);
      int my = (int)rintf(y*79.5f + 79.5f); my = min(max(my,0), GYD-1);
      int mz = (int)rintf(z*63.5f + 63.5f); mz = min(max(mz,0), GZD-1);
      int midx = mx*GYZ + my*GZD + mz;
      bool mm = (*flag) ? (((const unsigned char*)mask)[midx] != 0)
                        : (((const int*)mask)[midx] != 0);
      float e = __expf(pd + ACT_SHIFT);
      float alpha = 1.f - rsqrtf(1.f + e);   // (1+e)^(-0.5), INTERVAL=0.5
      if(!mm) alpha = 0.f;
      red[smp][3] = alpha;                   // rides out in rgba.w
      unsigned int d[8];
      #pragma unroll
      for(int j = 0; j < 6; ++j) d[j] = packbf(pf[2*j], pf[2*j+1]);
      d[6] = packbf(x, y);
      d[7] = packbf(z, __sinf(x));           // col 15 = sin(x * 2^0)
      uint4* p = (uint4*)(hA + smp*ROWA);
      p[0] = make_uint4(d[0],d[1],d[2],d[3]);
      p[1] = make_uint4(d[4],d[5],d[6],d[7]);
    } else if(corner == 1){
      uint4* p = (uint4*)(hA + smp*ROWA + 80);   // cols 80..95 zero
      p[0] = make_uint4(0,0,0,0);
      p[1] = make_uint4(0,0,0,0);
      ray_s[smp] = ray_id[i];
    }
    // corners 2,3: gather + butterfly only
  }

  // ---- phase 0b: posemb via double-angle recurrence. role j owns dim j -------
  // cols: sin dim j -> 15+10j .. 24+10j ; cos dim j -> 45+10j .. 54+10j
  // (col 15 = sin(x) is written by corner-0 above; role 0 skips it)
  {
    int j = tid >> 6, smp = tid & 63;
    unsigned short* row = hA + smp*ROWA;
    if(j < 3){
      float xv = xyz[3*(blk + smp) + j];
      float s[10], c[10];
      s[0] = __sinf(xv); c[0] = __cosf(xv);
      #pragma unroll
      for(int p = 1; p < 10; ++p){
        float sp = s[p-1], cp = c[p-1];
        s[p] = 2.f*sp*cp;
        c[p] = 1.f - 2.f*sp*sp;
      }
      int sb = 15 + 10*j, cb = 45 + 10*j;
      if(j) row[sb] = f2bf(s[0]);
      #pragma unroll
      for(int p = 0; p < 4; ++p)
        *(unsigned int*)(row + sb + 1 + 2*p) = packbf(s[1+2*p], s[2+2*p]);
      row[sb + 9] = f2bf(s[9]);
      row[cb] = f2bf(c[0]);
      #pragma unroll
      for(int p = 0; p < 4; ++p)
        *(unsigned int*)(row + cb + 1 + 2*p) = packbf(c[1+2*p], c[2+2*p]);
      row[cb + 9] = f2bf(c[9]);
    } else {
      row[75] = 0;
      *(unsigned int*)(row + 76) = 0;
      *(unsigned int*)(row + 78) = 0;
    }
  }
  __syncthreads();

  f32x16 acc0, acc1;

  // layer 0 (K=96): wf resident; prefetch layer-1 weights under epilogue
  mfma_layer<96, ROWA>(hA, wf, b0, wave, acc0, acc1, ln, kh);
  load_wf<8>(wt1 + (wave*32 + ln)*128 + kh*8, wf);
  epilogue<ROWB>(acc0, acc1, hB, wave, ln, kh);
  __syncthreads();

  // layer 1 (K=128)
  mfma_layer<128, ROWB>(hB, wf, b1, wave, acc0, acc1, ln, kh);
  load_wf<8>(wt2 + (wave*32 + ln)*128 + kh*8, wf);
  epilogue<ROWA>(acc0, acc1, hA, wave, ln, kh);
  __syncthreads();

  // layer 2 (K=128); prefetch head weights under epilogue
  int col = lane & 15, q4 = lane >> 4;
  mfma_layer<128, ROWA>(hA, wf, b2, wave, acc0, acc1, ln, kh);
  bf16x8 hw[4];
  {
    const unsigned short* wr = wtr + col*128 + q4*8;
    #pragma unroll
    for(int ks = 0; ks < 4; ++ks) hw[ks] = *(const bf16x8*)(wr + ks*32);
  }
  epilogue<ROWB>(acc0, acc1, hB, wave, ln, kh);
  // rayterm prefetch for head (ray_s valid since first sync)
  float rt[4] = {0.f, 0.f, 0.f, 0.f};
  if(col < 3){
    #pragma unroll
    for(int r = 0; r < 4; ++r)
      rt[r] = rayterm3[ray_s[wave*16 + q4*4 + r]*3 + col];
  }
  __syncthreads();

  // rgb head: 16x16x32 MFMA, K=128, 4 m-tiles = 4 waves; acc init = view term
  {
    int mt = wave;
    f32x4 acc = {rt[0], rt[1], rt[2], rt[3]};
    const unsigned short* arow = hB + (mt*16 + col)*ROWB + q4*8;
    __builtin_amdgcn_s_setprio(1);
    #pragma unroll
    for(int ks = 0; ks < 4; ++ks){
      bf16x8 af = *(const bf16x8*)(arow + ks*32);
      acc = __builtin_amdgcn_mfma_f32_16x16x32_bf16(af, hw[ks], acc, 0, 0, 0);
    }
    __builtin_amdgcn_s_setprio(0);
    if(col < 3){
      #pragma unroll
      for(int r = 0; r < 4; ++r){
        int sl = mt*16 + q4*4 + r;
        red[sl][col] = __fdividef(1.f, 1.f + __expf(-acc[r]));
      }
    }
  }
  __syncthreads();

  // coalesced rgba store (alpha in .w; composite happens in k_comp2)
  if(tid < SAMP){
    rgba_out[blk + tid] = make_float4(red[tid][0], red[tid][1], red[tid][2], red[tid][3]);
  }
}

// ---------------- per-ray: alpha scan + weighted composite in one pass ---------
__global__ __launch_bounds__(256) void k_comp2(const int* __restrict__ ray_id,
    const float4* __restrict__ rgba, float* __restrict__ out)
{
  int r = blockIdx.x*4 + (threadIdx.x >> 6);   // grid = NRAYS/4 blocks
  int lane = threadIdx.x & 63;
  int lo = 0, hi = M_SAMPLES;
  while(lo < hi){ int mid = (lo+hi) >> 1; if(ray_id[mid] < r) lo = mid+1; else hi = mid; }
  int s = lo;
  int lo2 = s, hi2 = M_SAMPLES;
  while(lo2 < hi2){ int mid = (lo2+hi2) >> 1; if(ray_id[mid] < r+1) lo2 = mid+1; else hi2 = mid; }
  int e = lo2;

  float carry = 1.f;
  float ar = 0.f, ag = 0.f, ab = 0.f;
  for(int base = s; base < e; base += 64){
    int idx = base + lane;
    float4 c = (idx < e) ? rgba[idx] : make_float4(0.f,0.f,0.f,0.f);
    float a = c.w;
    float incl = 1.f - a;
    #pragma unroll
    for(int d2 = 1; d2 < 64; d2 <<= 1){
      float t = __shfl_up(incl, d2);
      if(lane >= d2) incl *= t;
    }
    float excl = __shfl_up(incl, 1);
    if(lane == 0) excl = 1.f;
    float w = carry * excl * a;
    ar += w*c.x; ag += w*c.y; ab += w*c.z;
    carry *= __shfl(incl, 63);
  }
  #pragma unroll
  for(int m2 = 1; m2 < 64; m2 <<= 1){
    ar += __shfl_xor(ar, m2);
    ag += __shfl_xor(ag, m2);
    ab += __shfl_xor(ab, m2);
  }
  if(lane == 0){
    out[3*r+0] = ar + carry;
    out[3*r+1] = ag + carry;
    out[3*r+2] = ab + carry;
  }
}

// ---------------- host ----------------------------------------------------------
extern "C" void kernel_launch(void* const* d_in, const int* in_sizes, int n_in,
                              void* d_out, int out_size, void* d_ws, size_t ws_size,
                              hipStream_t stream)
{
  const float* xyz      = (const float*)d_in[0];
  const int*   ray_id   = (const int*)  d_in[1];
  const float* viewdirs = (const float*)d_in[2];
  const void*  mask     =               d_in[3];
  const float* density  = (const float*)d_in[4];
  const float* k0       = (const float*)d_in[5];
  const float* W0 = (const float*)d_in[6];  const float* b0 = (const float*)d_in[7];
  const float* W1 = (const float*)d_in[8];  const float* b1 = (const float*)d_in[9];
  const float* W2 = (const float*)d_in[10]; const float* b2 = (const float*)d_in[11];
  const float* Wr = (const float*)d_in[12]; const float* br = (const float*)d_in[13];
  float* out = (float*)d_out;

  char* ws = (char*)d_ws;
  size_t off = 0;
  auto take = [&](size_t nbytes) -> void* {
    void* p = ws + off;
    off = (off + nbytes + 255) & ~(size_t)255;
    return p;
  };
  int*            flag     = (int*)           take(4);
  unsigned short* wt0      = (unsigned short*)take(128*96*2);
  unsigned short* wt1      = (unsigned short*)take(128*128*2);
  unsigned short* wt2      = (unsigned short*)take(128*128*2);
  unsigned short* wtr      = (unsigned short*)take(16*128*2);
  float*          rayterm3 = (float*)         take((size_t)NRAYS*3*4);
  float4*         rgba_ws  = (float4*)        take((size_t)M_SAMPLES*16);
#ifdef HAVE_FP8
  uint4*          packed   = (uint4*)         take((size_t)NVOX*16);
#else
  uint4*          packed   = (uint4*)         take((size_t)NVOX*32);
#endif
  bool use_packed = (ws_size >= off);

  k_prep<<<NB_REPACK + 1 + NB_W + NB_RT, 256, 0, stream>>>(
      density, k0, packed, (const unsigned int*)mask, flag,
      W0, W1, W2, Wr, br, wt0, wt1, wt2, wtr, viewdirs, rayterm3);
  if(use_packed){
    k_mlp<1><<<M_SAMPLES/SAMP, 256, 0, stream>>>(xyz, packed, density, k0, mask, flag,
                                                 ray_id, wt0, wt1, wt2, wtr,
                                                 b0, b1, b2, rayterm3, rgba_ws);
  } else {
    k_mlp<0><<<M_SAMPLES/SAMP, 256, 0, stream>>>(xyz, packed, density, k0, mask, flag,
                                                 ray_id, wt0, wt1, wt2, wtr,
                                                 b0, b1, b2, rayterm3, rgba_ws);
  }
  k_comp2<<<NRAYS/4, 256, 0, stream>>>(ray_id, rgba_ws, out);
}